// Round 1
// 2760.524 us; speedup vs baseline: 2.3679x; 2.3679x over previous
//
#include <hip/hip_runtime.h>

// GraphEncoder: GINE-style GNN, D=768, 4 layers. fp32 I/O, f16 intermediates +
// f16 MFMA GEMMs, fp32 accumulate/LN/scatter math.
//
// Round 3: replace atomicAdd scatter (932us/layer, atomic-bound, 6x write
// amplification) with a once-built per-dst edge linked list + per-layer pure
// gather aggregation (in-register fp32 accumulate, fused z = h + agg).
//
// Workspace (~307 MiB, unchanged):
//   [WT 12x768x768 f16 | Q (50048x768 f16) | h (Nx768 f16) | e (Ex768 f16)]
// d_out (Nx768 fp32, 153.6MB) doubles as scratch: f16 U (<=76.9MB) in the low
// half; head[N]/next[E] (0.6MB) parked at +120MB (untouched until final LN).

#define DM 768
#define NLAYERS 4
#define CHUNK 50048  // bond-encoder row chunk (multiple of 128)

typedef _Float16 f16;
typedef __attribute__((ext_vector_type(8))) _Float16 f16x8;
typedef __attribute__((ext_vector_type(4))) _Float16 f16x4;
typedef __attribute__((ext_vector_type(4))) float f32x4;

__device__ __forceinline__ float gelu_f(float x) {
    float x3 = x * x * x;
    return 0.5f * x * (1.0f + tanhf(0.7978845608028654f * (x + 0.044715f * x3)));
}
__device__ __forceinline__ void async16(const void* g, void* l) {
    __builtin_amdgcn_global_load_lds((const __attribute__((address_space(1))) void*)g,
                                     (__attribute__((address_space(3))) void*)l,
                                     16, 0, 0);
}

__device__ __forceinline__ void block_reduce2(float& s1, float& s2, float* sm) {
    #pragma unroll
    for (int off = 32; off > 0; off >>= 1) {
        s1 += __shfl_down(s1, off);
        s2 += __shfl_down(s2, off);
    }
    int lane = threadIdx.x & 63, wid = threadIdx.x >> 6;
    if (lane == 0) { sm[wid * 2] = s1; sm[wid * 2 + 1] = s2; }
    __syncthreads();
    s1 = sm[0] + sm[2] + sm[4] + sm[6];
    s2 = sm[1] + sm[3] + sm[5] + sm[7];
}

// -------- weight transpose + fp32->fp16: Wt[n][k] = W[k][n], 768x768 ----------
__global__ __launch_bounds__(256) void transpose768(
    const float* __restrict__ W, f16* __restrict__ Wt) {
    __shared__ float t[32][33];
    int tx = threadIdx.x, ty = threadIdx.y;
    int c0 = blockIdx.x * 32, r0 = blockIdx.y * 32;
    #pragma unroll
    for (int j = 0; j < 32; j += 8) t[ty + j][tx] = W[(r0 + ty + j) * DM + c0 + tx];
    __syncthreads();
    #pragma unroll
    for (int j = 0; j < 32; j += 8) Wt[(long)(c0 + ty + j) * DM + r0 + tx] = (f16)t[tx][ty + j];
}

// -------- embedding-sum + LayerNorm (encoder front), fp32 in, fp16 out ----------
__global__ __launch_bounds__(256) void embed_ln_kernel(
    const int* __restrict__ ids, int F, int V,
    const float* __restrict__ emb,
    const float* __restrict__ g, const float* __restrict__ b,
    f16* __restrict__ out) {
    int m = blockIdx.x, tid = threadIdx.x;
    float v[3] = {0.f, 0.f, 0.f};
    for (int f = 0; f < F; ++f) {
        int id = ids[(long)m * F + f];
        const float* row = emb + ((long)f * V + id) * DM;
        v[0] += row[tid];
        v[1] += row[tid + 256];
        v[2] += row[tid + 512];
    }
    float s1 = v[0] + v[1] + v[2];
    float s2 = v[0] * v[0] + v[1] * v[1] + v[2] * v[2];
    __shared__ float sm[8];
    block_reduce2(s1, s2, sm);
    float mean = s1 * (1.f / DM);
    float var = s2 * (1.f / DM) - mean * mean;
    float rstd = rsqrtf(var + 1e-5f);
    #pragma unroll
    for (int q = 0; q < 3; ++q) {
        int d = tid + q * 256;
        out[(long)m * DM + d] = (f16)((v[q] - mean) * rstd * g[d] + b[d]);
    }
}

// -------- gelu(U) + h_in -> LayerNorm -> out ----------
template <typename OUT>
__global__ __launch_bounds__(256) void gelu_res_ln_kernel(
    const f16* __restrict__ U, const f16* __restrict__ hin,
    const float* __restrict__ g, const float* __restrict__ b,
    OUT* __restrict__ out) {
    int m = blockIdx.x, tid = threadIdx.x;
    float v[3];
    #pragma unroll
    for (int q = 0; q < 3; ++q) {
        int d = tid + q * 256;
        v[q] = gelu_f((float)U[(long)m * DM + d]) + (float)hin[(long)m * DM + d];
    }
    float s1 = v[0] + v[1] + v[2];
    float s2 = v[0] * v[0] + v[1] * v[1] + v[2] * v[2];
    __shared__ float sm[8];
    block_reduce2(s1, s2, sm);
    float mean = s1 * (1.f / DM);
    float var = s2 * (1.f / DM) - mean * mean;
    float rstd = rsqrtf(var + 1e-5f);
    #pragma unroll
    for (int q = 0; q < 3; ++q) {
        int d = tid + q * 256;
        out[(long)m * DM + d] = (OUT)((v[q] - mean) * rstd * g[d] + b[d]);
    }
}

// -------- build per-dst edge linked list (once; edge_index is layer-invariant) --
__global__ __launch_bounds__(256) void build_list_kernel(
    const int* __restrict__ ei, int E,
    int* __restrict__ head, int* __restrict__ nxt) {
    int e = blockIdx.x * 256 + threadIdx.x;
    if (e >= E) return;
    int dst = ei[E + e];
    nxt[e] = atomicExch(&head[dst], e);  // device-scope; order irrelevant (sum)
}

// -------- per-node gather aggregation: z[n] = h[n] + sum relu(h[src]+e) -------
// One wave per node; wave-uniform list walk (no divergence). 12 f16/lane (24B,
// 8B-aligned -> 3x f16x4 loads per row). fp32 in-register accumulate.
__global__ __launch_bounds__(256) void gather_agg_kernel(
    const int* __restrict__ ei,
    const int* __restrict__ head, const int* __restrict__ nxt,
    const f16* __restrict__ h, const f16* __restrict__ e,
    f16* __restrict__ z, int N) {
    int node = blockIdx.x * 4 + (threadIdx.x >> 6);
    if (node >= N) return;
    int lane = threadIdx.x & 63;
    int base = lane * 12;

    const f16* hr = h + (long)node * DM + base;
    f16x4 v0 = *(const f16x4*)&hr[0];
    f16x4 v1 = *(const f16x4*)&hr[4];
    f16x4 v2 = *(const f16x4*)&hr[8];
    float acc[12];
    #pragma unroll
    for (int j = 0; j < 4; ++j) {
        acc[j]     = (float)v0[j];
        acc[4 + j] = (float)v1[j];
        acc[8 + j] = (float)v2[j];
    }

    int ecur = head[node];
    while (ecur >= 0) {
        int enext = nxt[ecur];          // issue chase early; rows overlap it
        int src = ei[ecur];
        const f16* sr = h + (long)src * DM + base;
        const f16* er = e + (long)ecur * DM + base;
        f16x4 a0 = *(const f16x4*)&sr[0];
        f16x4 a1 = *(const f16x4*)&sr[4];
        f16x4 a2 = *(const f16x4*)&sr[8];
        f16x4 b0 = *(const f16x4*)&er[0];
        f16x4 b1 = *(const f16x4*)&er[4];
        f16x4 b2 = *(const f16x4*)&er[8];
        #pragma unroll
        for (int j = 0; j < 4; ++j) {
            float m0 = (float)a0[j] + (float)b0[j];
            float m1 = (float)a1[j] + (float)b1[j];
            float m2 = (float)a2[j] + (float)b2[j];
            if (m0 > 0.f) acc[j]     += m0;
            if (m1 > 0.f) acc[4 + j] += m1;
            if (m2 > 0.f) acc[8 + j] += m2;
        }
        ecur = enext;
    }

    f16* zr = z + (long)node * DM + base;
    f16x4 o0, o1, o2;
    #pragma unroll
    for (int j = 0; j < 4; ++j) {
        o0[j] = (f16)acc[j];
        o1[j] = (f16)acc[4 + j];
        o2[j] = (f16)acc[8 + j];
    }
    *(f16x4*)&zr[0] = o0;
    *(f16x4*)&zr[4] = o1;
    *(f16x4*)&zr[8] = o2;
}

// -------- GEMM: C[M,768] = act(A[M,768] @ W + bias), Bt[n][k] = W[k][n] ----------
#define ACT_NONE 0
#define ACT_RELU 1
#define ACT_GELU 2

template <int ACT>
__global__ __launch_bounds__(256, 2) void gemm768(
    const f16* __restrict__ A,      // [M,768] f16; rows may overread <=127 past M (mapped)
    const f16* __restrict__ Bt,     // [768,768] f16, Bt[n][k] = W[k][n]
    const float* __restrict__ bias, // [768] fp32
    f16* __restrict__ C,            // [M,768] f16
    int M) {
    __shared__ f16 As[128 * 32];
    __shared__ f16 Bs[128 * 32];
    int tid = threadIdx.x;
    int lane = tid & 63;
    int wid = tid >> 6;
    int wm = wid >> 1, wn = wid & 1;
    long rowBase = (long)blockIdx.x * 128;
    const f16* Ab = A + rowBase * DM;
    const f16* Bb = Bt + (long)blockIdx.y * 128 * DM;

    f32x4 acc[4][4];
    #pragma unroll
    for (int i = 0; i < 4; ++i)
        #pragma unroll
        for (int j = 0; j < 4; ++j) acc[i][j] = (f32x4){0.f, 0.f, 0.f, 0.f};

    int sr = wid * 32;
    int lr = lane >> 2;
    int lc = (lane & 3) * 8;
    int fm = lane & 15;
    int fk = (lane >> 4) * 8;

    for (int kt = 0; kt < DM / 32; ++kt) {
        int k0 = kt * 32;
        const f16* g0 = Ab + (long)(sr + lr) * DM + k0 + lc;
        async16(g0, &As[sr * 32]);
        async16(g0 + 16 * DM, &As[(sr + 16) * 32]);
        const f16* h0 = Bb + (long)(sr + lr) * DM + k0 + lc;
        async16(h0, &Bs[sr * 32]);
        async16(h0 + 16 * DM, &Bs[(sr + 16) * 32]);
        __syncthreads();

        f16x8 af[4], bfr[4];
        #pragma unroll
        for (int i = 0; i < 4; ++i)
            af[i] = *(const f16x8*)&As[(wm * 64 + i * 16 + fm) * 32 + fk];
        #pragma unroll
        for (int j = 0; j < 4; ++j)
            bfr[j] = *(const f16x8*)&Bs[(wn * 64 + j * 16 + fm) * 32 + fk];
        #pragma unroll
        for (int i = 0; i < 4; ++i)
            #pragma unroll
            for (int j = 0; j < 4; ++j)
                acc[i][j] = __builtin_amdgcn_mfma_f32_16x16x32_f16(af[i], bfr[j], acc[i][j], 0, 0, 0);
        __syncthreads();
    }

    int row0 = (int)rowBase + wm * 64;
    int col0 = blockIdx.y * 128 + wn * 64;
    #pragma unroll
    for (int j = 0; j < 4; ++j) {
        int c = col0 + j * 16 + (lane & 15);
        float bv = bias[c];
        #pragma unroll
        for (int i = 0; i < 4; ++i) {
            #pragma unroll
            for (int r = 0; r < 4; ++r) {
                int row = row0 + i * 16 + (lane >> 4) * 4 + r;
                if (row < M) {
                    float v = acc[i][j][r] + bv;
                    if (ACT == ACT_RELU) v = v > 0.f ? v : 0.f;
                    if (ACT == ACT_GELU) v = gelu_f(v);
                    C[(long)row * DM + c] = (f16)v;
                }
            }
        }
    }
}

extern "C" void kernel_launch(void* const* d_in, const int* in_sizes, int n_in,
                              void* d_out, int out_size, void* d_ws, size_t ws_size,
                              hipStream_t stream) {
    const int* x  = (const int*)d_in[0];
    const int* ea = (const int*)d_in[1];
    const int* ei = (const int*)d_in[2];
    const float* atom_emb  = (const float*)d_in[3];
    const float* atom_ln_g = (const float*)d_in[4];
    const float* atom_ln_b = (const float*)d_in[5];
    const float* atom_w1   = (const float*)d_in[6];
    const float* atom_b1   = (const float*)d_in[7];
    const float* atom_w2   = (const float*)d_in[8];
    const float* atom_b2   = (const float*)d_in[9];
    const float* bond_emb  = (const float*)d_in[10];
    const float* bond_ln_g = (const float*)d_in[11];
    const float* bond_ln_b = (const float*)d_in[12];
    const float* bond_w1   = (const float*)d_in[13];
    const float* bond_b1   = (const float*)d_in[14];
    const float* bond_w2   = (const float*)d_in[15];
    const float* bond_b2   = (const float*)d_in[16];
    const float* conv_w1   = (const float*)d_in[17];
    const float* conv_b1   = (const float*)d_in[18];
    const float* conv_w2   = (const float*)d_in[19];
    const float* conv_b2   = (const float*)d_in[20];
    const float* ln_g      = (const float*)d_in[21];
    const float* ln_b      = (const float*)d_in[22];

    const int N = in_sizes[0] / 9;
    const int E = in_sizes[1] / 3;
    const long SZ = (long)DM * DM;

    // ---- workspace: WT | Q | h | e  (~307 MiB total, unchanged) ----
    char* ws = (char*)d_ws;
    size_t off = 0;
    f16* WT = (f16*)(ws + off); off += ((size_t)12 * SZ * 2 + 4095) & ~(size_t)4095;
    f16* Q  = (f16*)(ws + off); off += ((size_t)CHUNK * DM * 2 + 4095) & ~(size_t)4095;
    f16* h  = (f16*)(ws + off); off += ((size_t)N * DM * 2 + 4095) & ~(size_t)4095;
    f16* e  = (f16*)(ws + off); off += ((size_t)E * DM * 2 + 4095) & ~(size_t)4095;
    // d_out region (N*DM fp32 = 153.6MB): low half = f16 U scratch (<=76.9MB);
    // head/next parked at +120MB, only clobbered by the final fp32 LN write.
    f16*   U    = (f16*)d_out;
    int*   head = (int*)((char*)d_out + 120000000);
    int*   nxt  = head + N;

    dim3 tb(32, 8), tg(24, 24);
    transpose768<<<tg, tb, 0, stream>>>(atom_w1, WT + 0 * SZ);
    transpose768<<<tg, tb, 0, stream>>>(atom_w2, WT + 1 * SZ);
    transpose768<<<tg, tb, 0, stream>>>(bond_w1, WT + 2 * SZ);
    transpose768<<<tg, tb, 0, stream>>>(bond_w2, WT + 3 * SZ);
    for (int l = 0; l < NLAYERS; ++l) {
        transpose768<<<tg, tb, 0, stream>>>(conv_w1 + l * SZ, WT + (4 + l) * SZ);
        transpose768<<<tg, tb, 0, stream>>>(conv_w2 + l * SZ, WT + (8 + l) * SZ);
    }

    // build dst->edges linked list once (edge_index is constant across layers)
    hipMemsetAsync(head, 0xFF, (size_t)N * 4, stream);  // head = -1
    build_list_kernel<<<(E + 255) / 256, 256, 0, stream>>>(ei, E, head, nxt);

    dim3 gn((N + 127) / 128, DM / 128);

    // AtomEncoder: h = gelu(LN(sum emb) @ w1 + b1) @ w2 + b2   (Q -> U(d_out) -> h)
    embed_ln_kernel<<<N, 256, 0, stream>>>(x, 9, 128, atom_emb, atom_ln_g, atom_ln_b, Q);
    gemm768<ACT_GELU><<<gn, 256, 0, stream>>>(Q, WT + 0 * SZ, atom_b1, U, N);
    gemm768<ACT_NONE><<<gn, 256, 0, stream>>>(U, WT + 1 * SZ, atom_b2, h, N);

    // BondEncoder in CHUNK-row chunks: Q -> U(d_out) -> e[c0..]
    for (int c0 = 0; c0 < E; c0 += CHUNK) {
        int rows = E - c0 < CHUNK ? E - c0 : CHUNK;
        dim3 gc((rows + 127) / 128, DM / 128);
        embed_ln_kernel<<<rows, 256, 0, stream>>>(ea + (long)c0 * 3, 3, 8,
                                                  bond_emb, bond_ln_g, bond_ln_b, Q);
        gemm768<ACT_GELU><<<gc, 256, 0, stream>>>(Q, WT + 2 * SZ, bond_b1, U, rows);
        gemm768<ACT_NONE><<<gc, 256, 0, stream>>>(U, WT + 3 * SZ, bond_b2, e + (long)c0 * DM, rows);
    }

    for (int l = 0; l < NLAYERS; ++l) {
        // z = h + sum_{j->i} relu(h[src] + e)  -> Q (f16), pure gather, no atomics
        gather_agg_kernel<<<(N + 3) / 4, 256, 0, stream>>>(ei, head, nxt, h, e, Q, N);
        gemm768<ACT_RELU><<<gn, 256, 0, stream>>>(Q, WT + (4 + l) * SZ, conv_b1 + l * DM, U, N);  // U -> d_out
        gemm768<ACT_NONE><<<gn, 256, 0, stream>>>(U, WT + (8 + l) * SZ, conv_b2 + l * DM, Q, N);  // V -> Q
        if (l == NLAYERS - 1) {
            gelu_res_ln_kernel<float><<<N, 256, 0, stream>>>(Q, h, ln_g + l * DM, ln_b + l * DM, (float*)d_out);
        } else {
            gelu_res_ln_kernel<f16><<<N, 256, 0, stream>>>(Q, h, ln_g + l * DM, ln_b + l * DM, h);
        }
    }
}

// Round 3
// 1971.883 us; speedup vs baseline: 3.3149x; 1.3999x over previous
//
#include <hip/hip_runtime.h>

// GraphEncoder: GINE-style GNN, D=768, 4 layers. fp32 I/O, f16 intermediates +
// f16 MFMA GEMMs, fp32 accumulate/LN/scatter math.
//
// Round 5 (resubmit of round 4 — container infra failure, no counters):
//  - Bond encoder deduped: edge_attr has 3 feats x vocab 8 -> 512 combos.
//    Encode all 512 once (two M=512 GEMMs), gather via per-edge key in the
//    aggregation kernel. Deletes 4 big GEMMs + the 153.6MB e buffer.
//  - gemm768 grid swapped to column-fastest (6 col-blocks of a row-tile run
//    concurrently -> A fetched from HBM once, not 3x).
//  - LDS XOR-swizzle (slot ^= (row>>1)&3) on both staging source and ds_read
//    (both-sides rule): 8-way bank conflict -> conflict-free.
//
// Workspace: [WT 12x768x768 f16 | Q 50048x768 f16 | h Nx768 f16 | T | key | ids3]
// d_out (Nx768 fp32, 153.6MB): low half = f16 U scratch; head/next parked at
// +120MB (clobbered only by the final fp32 LN write, which covers all of d_out).

#define DM 768
#define NLAYERS 4
#define CHUNK 50048  // row capacity for Q (multiple of 128, >= N)

typedef _Float16 f16;
typedef __attribute__((ext_vector_type(8))) _Float16 f16x8;
typedef __attribute__((ext_vector_type(4))) _Float16 f16x4;
typedef __attribute__((ext_vector_type(4))) float f32x4;

__device__ __forceinline__ float gelu_f(float x) {
    float x3 = x * x * x;
    return 0.5f * x * (1.0f + tanhf(0.7978845608028654f * (x + 0.044715f * x3)));
}
__device__ __forceinline__ void async16(const void* g, void* l) {
    __builtin_amdgcn_global_load_lds((const __attribute__((address_space(1))) void*)g,
                                     (__attribute__((address_space(3))) void*)l,
                                     16, 0, 0);
}

__device__ __forceinline__ void block_reduce2(float& s1, float& s2, float* sm) {
    #pragma unroll
    for (int off = 32; off > 0; off >>= 1) {
        s1 += __shfl_down(s1, off);
        s2 += __shfl_down(s2, off);
    }
    int lane = threadIdx.x & 63, wid = threadIdx.x >> 6;
    if (lane == 0) { sm[wid * 2] = s1; sm[wid * 2 + 1] = s2; }
    __syncthreads();
    s1 = sm[0] + sm[2] + sm[4] + sm[6];
    s2 = sm[1] + sm[3] + sm[5] + sm[7];
}

// -------- weight transpose + fp32->fp16: Wt[n][k] = W[k][n], 768x768 ----------
__global__ __launch_bounds__(256) void transpose768(
    const float* __restrict__ W, f16* __restrict__ Wt) {
    __shared__ float t[32][33];
    int tx = threadIdx.x, ty = threadIdx.y;
    int c0 = blockIdx.x * 32, r0 = blockIdx.y * 32;
    #pragma unroll
    for (int j = 0; j < 32; j += 8) t[ty + j][tx] = W[(r0 + ty + j) * DM + c0 + tx];
    __syncthreads();
    #pragma unroll
    for (int j = 0; j < 32; j += 8) Wt[(long)(c0 + ty + j) * DM + r0 + tx] = (f16)t[tx][ty + j];
}

// -------- embedding-sum + LayerNorm (encoder front), fp32 in, fp16 out ----------
__global__ __launch_bounds__(256) void embed_ln_kernel(
    const int* __restrict__ ids, int F, int V,
    const float* __restrict__ emb,
    const float* __restrict__ g, const float* __restrict__ b,
    f16* __restrict__ out) {
    int m = blockIdx.x, tid = threadIdx.x;
    float v[3] = {0.f, 0.f, 0.f};
    for (int f = 0; f < F; ++f) {
        int id = ids[(long)m * F + f];
        const float* row = emb + ((long)f * V + id) * DM;
        v[0] += row[tid];
        v[1] += row[tid + 256];
        v[2] += row[tid + 512];
    }
    float s1 = v[0] + v[1] + v[2];
    float s2 = v[0] * v[0] + v[1] * v[1] + v[2] * v[2];
    __shared__ float sm[8];
    block_reduce2(s1, s2, sm);
    float mean = s1 * (1.f / DM);
    float var = s2 * (1.f / DM) - mean * mean;
    float rstd = rsqrtf(var + 1e-5f);
    #pragma unroll
    for (int q = 0; q < 3; ++q) {
        int d = tid + q * 256;
        out[(long)m * DM + d] = (f16)((v[q] - mean) * rstd * g[d] + b[d]);
    }
}

// -------- gelu(U) + h_in -> LayerNorm -> out ----------
template <typename OUT>
__global__ __launch_bounds__(256) void gelu_res_ln_kernel(
    const f16* __restrict__ U, const f16* __restrict__ hin,
    const float* __restrict__ g, const float* __restrict__ b,
    OUT* __restrict__ out) {
    int m = blockIdx.x, tid = threadIdx.x;
    float v[3];
    #pragma unroll
    for (int q = 0; q < 3; ++q) {
        int d = tid + q * 256;
        v[q] = gelu_f((float)U[(long)m * DM + d]) + (float)hin[(long)m * DM + d];
    }
    float s1 = v[0] + v[1] + v[2];
    float s2 = v[0] * v[0] + v[1] * v[1] + v[2] * v[2];
    __shared__ float sm[8];
    block_reduce2(s1, s2, sm);
    float mean = s1 * (1.f / DM);
    float var = s2 * (1.f / DM) - mean * mean;
    float rstd = rsqrtf(var + 1e-5f);
    #pragma unroll
    for (int q = 0; q < 3; ++q) {
        int d = tid + q * 256;
        out[(long)m * DM + d] = (OUT)((v[q] - mean) * rstd * g[d] + b[d]);
    }
}

// -------- bond-combo helpers: ids for all V^3 combos; per-edge key ----------
__global__ __launch_bounds__(256) void make_combo_ids(
    int V, int nC, int* __restrict__ ids) {
    int c = blockIdx.x * 256 + threadIdx.x;
    if (c >= nC) return;
    ids[c * 3 + 0] = c / (V * V);
    ids[c * 3 + 1] = (c / V) % V;
    ids[c * 3 + 2] = c % V;
}
__global__ __launch_bounds__(256) void make_key_kernel(
    const int* __restrict__ ea, int E, int V, int* __restrict__ key) {
    int e = blockIdx.x * 256 + threadIdx.x;
    if (e >= E) return;
    key[e] = (ea[e * 3 + 0] * V + ea[e * 3 + 1]) * V + ea[e * 3 + 2];
}

// -------- build per-dst edge linked list (once; edge_index is layer-invariant) --
__global__ __launch_bounds__(256) void build_list_kernel(
    const int* __restrict__ ei, int E,
    int* __restrict__ head, int* __restrict__ nxt) {
    int e = blockIdx.x * 256 + threadIdx.x;
    if (e >= E) return;
    int dst = ei[E + e];
    nxt[e] = atomicExch(&head[dst], e);  // device-scope; order irrelevant (sum)
}

// -------- per-node gather aggregation: z[n] = h[n] + sum relu(h[src]+T[key]) --
// One wave per node; wave-uniform list walk (no divergence). 12 f16/lane.
// fp32 in-register accumulate. Edge features come from the 512-row combo
// table T (L2-resident) via key[edge].
__global__ __launch_bounds__(256) void gather_agg_kernel(
    const int* __restrict__ ei,
    const int* __restrict__ head, const int* __restrict__ nxt,
    const int* __restrict__ key,
    const f16* __restrict__ h, const f16* __restrict__ T,
    f16* __restrict__ z, int N) {
    int node = blockIdx.x * 4 + (threadIdx.x >> 6);
    if (node >= N) return;
    int lane = threadIdx.x & 63;
    int base = lane * 12;

    const f16* hr = h + (long)node * DM + base;
    f16x4 v0 = *(const f16x4*)&hr[0];
    f16x4 v1 = *(const f16x4*)&hr[4];
    f16x4 v2 = *(const f16x4*)&hr[8];
    float acc[12];
    #pragma unroll
    for (int j = 0; j < 4; ++j) {
        acc[j]     = (float)v0[j];
        acc[4 + j] = (float)v1[j];
        acc[8 + j] = (float)v2[j];
    }

    int ecur = head[node];
    while (ecur >= 0) {
        int enext = nxt[ecur];          // issue chase early; rows overlap it
        int src = ei[ecur];
        int kq = key[ecur];
        const f16* sr = h + (long)src * DM + base;
        const f16* er = T + (long)kq * DM + base;
        f16x4 a0 = *(const f16x4*)&sr[0];
        f16x4 a1 = *(const f16x4*)&sr[4];
        f16x4 a2 = *(const f16x4*)&sr[8];
        f16x4 b0 = *(const f16x4*)&er[0];
        f16x4 b1 = *(const f16x4*)&er[4];
        f16x4 b2 = *(const f16x4*)&er[8];
        #pragma unroll
        for (int j = 0; j < 4; ++j) {
            float m0 = (float)a0[j] + (float)b0[j];
            float m1 = (float)a1[j] + (float)b1[j];
            float m2 = (float)a2[j] + (float)b2[j];
            if (m0 > 0.f) acc[j]     += m0;
            if (m1 > 0.f) acc[4 + j] += m1;
            if (m2 > 0.f) acc[8 + j] += m2;
        }
        ecur = enext;
    }

    f16* zr = z + (long)node * DM + base;
    f16x4 o0, o1, o2;
    #pragma unroll
    for (int j = 0; j < 4; ++j) {
        o0[j] = (f16)acc[j];
        o1[j] = (f16)acc[4 + j];
        o2[j] = (f16)acc[8 + j];
    }
    *(f16x4*)&zr[0] = o0;
    *(f16x4*)&zr[4] = o1;
    *(f16x4*)&zr[8] = o2;
}

// -------- GEMM: C[M,768] = act(A[M,768] @ W + bias), Bt[n][k] = W[k][n] ----------
// Grid: (DM/128 col-blocks, rowTiles) -- column-fastest so the 6 col-blocks of
// one row-tile run concurrently and share the A tile via L2/L3.
// LDS tiles [128][32] f16 are XOR-swizzled: slot(16B) ^= (row>>1)&3, applied to
// BOTH the global_load_lds source column and the ds_read offset (rule #21).
#define ACT_NONE 0
#define ACT_RELU 1
#define ACT_GELU 2

template <int ACT>
__global__ __launch_bounds__(256, 2) void gemm768(
    const f16* __restrict__ A,      // [M,768] f16; rows may overread <=127 past M (mapped)
    const f16* __restrict__ Bt,     // [768,768] f16, Bt[n][k] = W[k][n]
    const float* __restrict__ bias, // [768] fp32
    f16* __restrict__ C,            // [M,768] f16
    int M) {
    __shared__ f16 As[128 * 32];
    __shared__ f16 Bs[128 * 32];
    int tid = threadIdx.x;
    int lane = tid & 63;
    int wid = tid >> 6;
    int wm = wid >> 1, wn = wid & 1;
    long rowBase = (long)blockIdx.y * 128;
    const f16* Ab = A + rowBase * DM;
    const f16* Bb = Bt + (long)blockIdx.x * 128 * DM;

    f32x4 acc[4][4];
    #pragma unroll
    for (int i = 0; i < 4; ++i)
        #pragma unroll
        for (int j = 0; j < 4; ++j) acc[i][j] = (f32x4){0.f, 0.f, 0.f, 0.f};

    int sr = wid * 32;
    int lr = lane >> 2;
    // staging source column: slot (lane&3) XOR'd with (row>>1)&3 == (lr>>1)&3
    int lc = (((lane & 3) ^ ((lr >> 1) & 3)) * 8);
    int fm = lane & 15;
    int fk = (lane >> 4) * 8;
    // ds_read offset: slot fk/8 XOR'd with (row>>1)&3 == (fm>>1)&3
    int fs = fk ^ (((fm >> 1) & 3) << 3);

    for (int kt = 0; kt < DM / 32; ++kt) {
        int k0 = kt * 32;
        const f16* g0 = Ab + (long)(sr + lr) * DM + k0 + lc;
        async16(g0, &As[sr * 32]);
        async16(g0 + 16 * DM, &As[(sr + 16) * 32]);
        const f16* h0 = Bb + (long)(sr + lr) * DM + k0 + lc;
        async16(h0, &Bs[sr * 32]);
        async16(h0 + 16 * DM, &Bs[(sr + 16) * 32]);
        __syncthreads();

        f16x8 af[4], bfr[4];
        #pragma unroll
        for (int i = 0; i < 4; ++i)
            af[i] = *(const f16x8*)&As[(wm * 64 + i * 16 + fm) * 32 + fs];
        #pragma unroll
        for (int j = 0; j < 4; ++j)
            bfr[j] = *(const f16x8*)&Bs[(wn * 64 + j * 16 + fm) * 32 + fs];
        #pragma unroll
        for (int i = 0; i < 4; ++i)
            #pragma unroll
            for (int j = 0; j < 4; ++j)
                acc[i][j] = __builtin_amdgcn_mfma_f32_16x16x32_f16(af[i], bfr[j], acc[i][j], 0, 0, 0);
        __syncthreads();
    }

    int row0 = (int)rowBase + wm * 64;
    int col0 = blockIdx.x * 128 + wn * 64;
    #pragma unroll
    for (int j = 0; j < 4; ++j) {
        int c = col0 + j * 16 + (lane & 15);
        float bv = bias[c];
        #pragma unroll
        for (int i = 0; i < 4; ++i) {
            #pragma unroll
            for (int r = 0; r < 4; ++r) {
                int row = row0 + i * 16 + (lane >> 4) * 4 + r;
                if (row < M) {
                    float v = acc[i][j][r] + bv;
                    if (ACT == ACT_RELU) v = v > 0.f ? v : 0.f;
                    if (ACT == ACT_GELU) v = gelu_f(v);
                    C[(long)row * DM + c] = (f16)v;
                }
            }
        }
    }
}

extern "C" void kernel_launch(void* const* d_in, const int* in_sizes, int n_in,
                              void* d_out, int out_size, void* d_ws, size_t ws_size,
                              hipStream_t stream) {
    const int* x  = (const int*)d_in[0];
    const int* ea = (const int*)d_in[1];
    const int* ei = (const int*)d_in[2];
    const float* atom_emb  = (const float*)d_in[3];
    const float* atom_ln_g = (const float*)d_in[4];
    const float* atom_ln_b = (const float*)d_in[5];
    const float* atom_w1   = (const float*)d_in[6];
    const float* atom_b1   = (const float*)d_in[7];
    const float* atom_w2   = (const float*)d_in[8];
    const float* atom_b2   = (const float*)d_in[9];
    const float* bond_emb  = (const float*)d_in[10];
    const float* bond_ln_g = (const float*)d_in[11];
    const float* bond_ln_b = (const float*)d_in[12];
    const float* bond_w1   = (const float*)d_in[13];
    const float* bond_b1   = (const float*)d_in[14];
    const float* bond_w2   = (const float*)d_in[15];
    const float* bond_b2   = (const float*)d_in[16];
    const float* conv_w1   = (const float*)d_in[17];
    const float* conv_b1   = (const float*)d_in[18];
    const float* conv_w2   = (const float*)d_in[19];
    const float* conv_b2   = (const float*)d_in[20];
    const float* ln_g      = (const float*)d_in[21];
    const float* ln_b      = (const float*)d_in[22];

    const int N = in_sizes[0] / 9;
    const int E = in_sizes[1] / 3;
    const int V = in_sizes[10] / (3 * DM);  // bond vocab (8) -> V^3 combos (512)
    const int nC = V * V * V;
    const long SZ = (long)DM * DM;

    // ---- workspace: WT | Q | h | T | key | ids3 (~170 MiB) ----
    char* ws = (char*)d_ws;
    size_t off = 0;
    f16* WT  = (f16*)(ws + off); off += ((size_t)12 * SZ * 2 + 4095) & ~(size_t)4095;
    f16* Q   = (f16*)(ws + off); off += ((size_t)CHUNK * DM * 2 + 4095) & ~(size_t)4095;
    f16* h   = (f16*)(ws + off); off += ((size_t)N * DM * 2 + 4095) & ~(size_t)4095;
    f16* T   = (f16*)(ws + off); off += ((size_t)((nC + 127) & ~127) * DM * 2 + 4095) & ~(size_t)4095;
    int* key = (int*)(ws + off); off += ((size_t)E * 4 + 4095) & ~(size_t)4095;
    int* ids3 = (int*)(ws + off); off += ((size_t)nC * 12 + 4095) & ~(size_t)4095;
    // d_out region (N*DM fp32 = 153.6MB): low half = f16 U scratch (<=76.9MB);
    // head/next parked at +120MB, only clobbered by the final fp32 LN write.
    f16*   U    = (f16*)d_out;
    int*   head = (int*)((char*)d_out + 120000000);
    int*   nxt  = head + N;

    dim3 tb(32, 8), tg(24, 24);
    transpose768<<<tg, tb, 0, stream>>>(atom_w1, WT + 0 * SZ);
    transpose768<<<tg, tb, 0, stream>>>(atom_w2, WT + 1 * SZ);
    transpose768<<<tg, tb, 0, stream>>>(bond_w1, WT + 2 * SZ);
    transpose768<<<tg, tb, 0, stream>>>(bond_w2, WT + 3 * SZ);
    for (int l = 0; l < NLAYERS; ++l) {
        transpose768<<<tg, tb, 0, stream>>>(conv_w1 + l * SZ, WT + (4 + l) * SZ);
        transpose768<<<tg, tb, 0, stream>>>(conv_w2 + l * SZ, WT + (8 + l) * SZ);
    }

    // build dst->edges linked list + per-edge combo key (edge data is constant)
    hipMemsetAsync(head, 0xFF, (size_t)N * 4, stream);  // head = -1
    build_list_kernel<<<(E + 255) / 256, 256, 0, stream>>>(ei, E, head, nxt);
    make_key_kernel<<<(E + 255) / 256, 256, 0, stream>>>(ea, E, V, key);

    dim3 gn(DM / 128, (N + 127) / 128);   // column-fastest

    // AtomEncoder: h = gelu(LN(sum emb) @ w1 + b1) @ w2 + b2   (Q -> U(d_out) -> h)
    embed_ln_kernel<<<N, 256, 0, stream>>>(x, 9, 128, atom_emb, atom_ln_g, atom_ln_b, Q);
    gemm768<ACT_GELU><<<gn, 256, 0, stream>>>(Q, WT + 0 * SZ, atom_b1, U, N);
    gemm768<ACT_NONE><<<gn, 256, 0, stream>>>(U, WT + 1 * SZ, atom_b2, h, N);

    // BondEncoder on the V^3 combo table only: Q -> U(d_out) -> T
    make_combo_ids<<<(nC + 255) / 256, 256, 0, stream>>>(V, nC, ids3);
    embed_ln_kernel<<<nC, 256, 0, stream>>>(ids3, 3, V, bond_emb, bond_ln_g, bond_ln_b, Q);
    dim3 gt(DM / 128, (nC + 127) / 128);
    gemm768<ACT_GELU><<<gt, 256, 0, stream>>>(Q, WT + 2 * SZ, bond_b1, U, nC);
    gemm768<ACT_NONE><<<gt, 256, 0, stream>>>(U, WT + 3 * SZ, bond_b2, T, nC);

    for (int l = 0; l < NLAYERS; ++l) {
        // z = h + sum_{j->i} relu(h[src] + T[key])  -> Q (f16), pure gather
        gather_agg_kernel<<<(N + 3) / 4, 256, 0, stream>>>(ei, head, nxt, key, h, T, Q, N);
        gemm768<ACT_RELU><<<gn, 256, 0, stream>>>(Q, WT + (4 + l) * SZ, conv_b1 + l * DM, U, N);  // U -> d_out
        gemm768<ACT_NONE><<<gn, 256, 0, stream>>>(U, WT + (8 + l) * SZ, conv_b2 + l * DM, Q, N);  // V -> Q
        if (l == NLAYERS - 1) {
            gelu_res_ln_kernel<float><<<N, 256, 0, stream>>>(Q, h, ln_g + l * DM, ln_b + l * DM, (float*)d_out);
        } else {
            gelu_res_ln_kernel<f16><<<N, 256, 0, stream>>>(Q, h, ln_g + l * DM, ln_b + l * DM, h);
        }
    }
}

// Round 4
// 1880.442 us; speedup vs baseline: 3.4761x; 1.0486x over previous
//
#include <hip/hip_runtime.h>

// GraphEncoder: GINE-style GNN, D=768, 4 layers. fp32 I/O, f16 intermediates +
// f16 MFMA GEMMs, fp32 accumulate/LN/scatter math.
//
// Round 6: GEMM grid -> 1-D with bijective XCD-chunked swizzle (m204). The 6
// col-blocks of a row-tile now run on the SAME XCD (col-fastest within the
// XCD's contiguous chunk), so A row-tiles are fetched once into that XCD's
// private L2 instead of ~6x across XCDs (round-3 counters: FETCH 238MB vs
// 78MB ideal; col-fastest 2-D grid scattered same-row-tile blocks over XCDs).
// B (1.2MB) stays L2-resident per XCD across all its row tiles.
//
// Workspace: [WT 12x768x768 f16 | Q 50048x768 f16 | h Nx768 f16 | T | key | ids3]
// d_out (Nx768 fp32, 153.6MB): low half = f16 U scratch; head/next parked at
// +120MB (clobbered only by the final fp32 LN write, which covers all of d_out).

#define DM 768
#define NLAYERS 4
#define CHUNK 50048  // row capacity for Q (multiple of 128, >= N)

typedef _Float16 f16;
typedef __attribute__((ext_vector_type(8))) _Float16 f16x8;
typedef __attribute__((ext_vector_type(4))) _Float16 f16x4;
typedef __attribute__((ext_vector_type(4))) float f32x4;

__device__ __forceinline__ float gelu_f(float x) {
    float x3 = x * x * x;
    return 0.5f * x * (1.0f + tanhf(0.7978845608028654f * (x + 0.044715f * x3)));
}
__device__ __forceinline__ void async16(const void* g, void* l) {
    __builtin_amdgcn_global_load_lds((const __attribute__((address_space(1))) void*)g,
                                     (__attribute__((address_space(3))) void*)l,
                                     16, 0, 0);
}

// bijective XCD-chunked swizzle (m204): XCD k = b%8 gets a contiguous range of
// work ids; within the range, original b/8 order is preserved.
__device__ __forceinline__ int xcd_swizzle(int b, int nb) {
    int xcd = b & 7;
    int pos = b >> 3;
    int q = nb >> 3, r = nb & 7;
    int base = (xcd < r) ? xcd * (q + 1) : r * (q + 1) + (xcd - r) * q;
    return base + pos;
}

__device__ __forceinline__ void block_reduce2(float& s1, float& s2, float* sm) {
    #pragma unroll
    for (int off = 32; off > 0; off >>= 1) {
        s1 += __shfl_down(s1, off);
        s2 += __shfl_down(s2, off);
    }
    int lane = threadIdx.x & 63, wid = threadIdx.x >> 6;
    if (lane == 0) { sm[wid * 2] = s1; sm[wid * 2 + 1] = s2; }
    __syncthreads();
    s1 = sm[0] + sm[2] + sm[4] + sm[6];
    s2 = sm[1] + sm[3] + sm[5] + sm[7];
}

// -------- weight transpose + fp32->fp16: Wt[n][k] = W[k][n], 768x768 ----------
__global__ __launch_bounds__(256) void transpose768(
    const float* __restrict__ W, f16* __restrict__ Wt) {
    __shared__ float t[32][33];
    int tx = threadIdx.x, ty = threadIdx.y;
    int c0 = blockIdx.x * 32, r0 = blockIdx.y * 32;
    #pragma unroll
    for (int j = 0; j < 32; j += 8) t[ty + j][tx] = W[(r0 + ty + j) * DM + c0 + tx];
    __syncthreads();
    #pragma unroll
    for (int j = 0; j < 32; j += 8) Wt[(long)(c0 + ty + j) * DM + r0 + tx] = (f16)t[tx][ty + j];
}

// -------- embedding-sum + LayerNorm (encoder front), fp32 in, fp16 out ----------
__global__ __launch_bounds__(256) void embed_ln_kernel(
    const int* __restrict__ ids, int F, int V,
    const float* __restrict__ emb,
    const float* __restrict__ g, const float* __restrict__ b,
    f16* __restrict__ out) {
    int m = blockIdx.x, tid = threadIdx.x;
    float v[3] = {0.f, 0.f, 0.f};
    for (int f = 0; f < F; ++f) {
        int id = ids[(long)m * F + f];
        const float* row = emb + ((long)f * V + id) * DM;
        v[0] += row[tid];
        v[1] += row[tid + 256];
        v[2] += row[tid + 512];
    }
    float s1 = v[0] + v[1] + v[2];
    float s2 = v[0] * v[0] + v[1] * v[1] + v[2] * v[2];
    __shared__ float sm[8];
    block_reduce2(s1, s2, sm);
    float mean = s1 * (1.f / DM);
    float var = s2 * (1.f / DM) - mean * mean;
    float rstd = rsqrtf(var + 1e-5f);
    #pragma unroll
    for (int q = 0; q < 3; ++q) {
        int d = tid + q * 256;
        out[(long)m * DM + d] = (f16)((v[q] - mean) * rstd * g[d] + b[d]);
    }
}

// -------- gelu(U) + h_in -> LayerNorm -> out ----------
template <typename OUT>
__global__ __launch_bounds__(256) void gelu_res_ln_kernel(
    const f16* __restrict__ U, const f16* __restrict__ hin,
    const float* __restrict__ g, const float* __restrict__ b,
    OUT* __restrict__ out) {
    int m = blockIdx.x, tid = threadIdx.x;
    float v[3];
    #pragma unroll
    for (int q = 0; q < 3; ++q) {
        int d = tid + q * 256;
        v[q] = gelu_f((float)U[(long)m * DM + d]) + (float)hin[(long)m * DM + d];
    }
    float s1 = v[0] + v[1] + v[2];
    float s2 = v[0] * v[0] + v[1] * v[1] + v[2] * v[2];
    __shared__ float sm[8];
    block_reduce2(s1, s2, sm);
    float mean = s1 * (1.f / DM);
    float var = s2 * (1.f / DM) - mean * mean;
    float rstd = rsqrtf(var + 1e-5f);
    #pragma unroll
    for (int q = 0; q < 3; ++q) {
        int d = tid + q * 256;
        out[(long)m * DM + d] = (OUT)((v[q] - mean) * rstd * g[d] + b[d]);
    }
}

// -------- bond-combo helpers: ids for all V^3 combos; per-edge key ----------
__global__ __launch_bounds__(256) void make_combo_ids(
    int V, int nC, int* __restrict__ ids) {
    int c = blockIdx.x * 256 + threadIdx.x;
    if (c >= nC) return;
    ids[c * 3 + 0] = c / (V * V);
    ids[c * 3 + 1] = (c / V) % V;
    ids[c * 3 + 2] = c % V;
}
__global__ __launch_bounds__(256) void make_key_kernel(
    const int* __restrict__ ea, int E, int V, int* __restrict__ key) {
    int e = blockIdx.x * 256 + threadIdx.x;
    if (e >= E) return;
    key[e] = (ea[e * 3 + 0] * V + ea[e * 3 + 1]) * V + ea[e * 3 + 2];
}

// -------- build per-dst edge linked list (once; edge_index is layer-invariant) --
__global__ __launch_bounds__(256) void build_list_kernel(
    const int* __restrict__ ei, int E,
    int* __restrict__ head, int* __restrict__ nxt) {
    int e = blockIdx.x * 256 + threadIdx.x;
    if (e >= E) return;
    int dst = ei[E + e];
    nxt[e] = atomicExch(&head[dst], e);  // device-scope; order irrelevant (sum)
}

// -------- per-node gather aggregation: z[n] = h[n] + sum relu(h[src]+T[key]) --
// One wave per node; wave-uniform list walk (no divergence). 12 f16/lane.
// fp32 in-register accumulate. Edge features come from the 512-row combo
// table T (L2-resident) via key[edge].
__global__ __launch_bounds__(256) void gather_agg_kernel(
    const int* __restrict__ ei,
    const int* __restrict__ head, const int* __restrict__ nxt,
    const int* __restrict__ key,
    const f16* __restrict__ h, const f16* __restrict__ T,
    f16* __restrict__ z, int N) {
    int node = blockIdx.x * 4 + (threadIdx.x >> 6);
    if (node >= N) return;
    int lane = threadIdx.x & 63;
    int base = lane * 12;

    const f16* hr = h + (long)node * DM + base;
    f16x4 v0 = *(const f16x4*)&hr[0];
    f16x4 v1 = *(const f16x4*)&hr[4];
    f16x4 v2 = *(const f16x4*)&hr[8];
    float acc[12];
    #pragma unroll
    for (int j = 0; j < 4; ++j) {
        acc[j]     = (float)v0[j];
        acc[4 + j] = (float)v1[j];
        acc[8 + j] = (float)v2[j];
    }

    int ecur = head[node];
    while (ecur >= 0) {
        int enext = nxt[ecur];          // issue chase early; rows overlap it
        int src = ei[ecur];
        int kq = key[ecur];
        const f16* sr = h + (long)src * DM + base;
        const f16* er = T + (long)kq * DM + base;
        f16x4 a0 = *(const f16x4*)&sr[0];
        f16x4 a1 = *(const f16x4*)&sr[4];
        f16x4 a2 = *(const f16x4*)&sr[8];
        f16x4 b0 = *(const f16x4*)&er[0];
        f16x4 b1 = *(const f16x4*)&er[4];
        f16x4 b2 = *(const f16x4*)&er[8];
        #pragma unroll
        for (int j = 0; j < 4; ++j) {
            float m0 = (float)a0[j] + (float)b0[j];
            float m1 = (float)a1[j] + (float)b1[j];
            float m2 = (float)a2[j] + (float)b2[j];
            if (m0 > 0.f) acc[j]     += m0;
            if (m1 > 0.f) acc[4 + j] += m1;
            if (m2 > 0.f) acc[8 + j] += m2;
        }
        ecur = enext;
    }

    f16* zr = z + (long)node * DM + base;
    f16x4 o0, o1, o2;
    #pragma unroll
    for (int j = 0; j < 4; ++j) {
        o0[j] = (f16)acc[j];
        o1[j] = (f16)acc[4 + j];
        o2[j] = (f16)acc[8 + j];
    }
    *(f16x4*)&zr[0] = o0;
    *(f16x4*)&zr[4] = o1;
    *(f16x4*)&zr[8] = o2;
}

// -------- GEMM: C[M,768] = act(A[M,768] @ W + bias), Bt[n][k] = W[k][n] ----------
// 1-D grid of 6*rowTiles blocks, XCD-chunked swizzle: each XCD gets contiguous
// work ids, enumerated col-fastest (6 col-blocks of a row-tile consecutive) so
// A tiles are fetched once into that XCD's L2 and B stays L2-resident per XCD.
// LDS tiles [128][32] f16 are XOR-swizzled: slot(16B) ^= (row>>1)&3, applied to
// BOTH the global_load_lds source column and the ds_read offset (rule #21).
#define ACT_NONE 0
#define ACT_RELU 1
#define ACT_GELU 2

template <int ACT>
__global__ __launch_bounds__(256, 2) void gemm768(
    const f16* __restrict__ A,      // [M,768] f16; rows may overread <=127 past M (mapped)
    const f16* __restrict__ Bt,     // [768,768] f16, Bt[n][k] = W[k][n]
    const float* __restrict__ bias, // [768] fp32
    f16* __restrict__ C,            // [M,768] f16
    int M) {
    __shared__ f16 As[128 * 32];
    __shared__ f16 Bs[128 * 32];
    int tid = threadIdx.x;
    int lane = tid & 63;
    int wid = tid >> 6;
    int wm = wid >> 1, wn = wid & 1;

    int wg = xcd_swizzle(blockIdx.x, gridDim.x);
    int rt = wg / 6, cb = wg - rt * 6;
    long rowBase = (long)rt * 128;
    const f16* Ab = A + rowBase * DM;
    const f16* Bb = Bt + (long)cb * 128 * DM;

    f32x4 acc[4][4];
    #pragma unroll
    for (int i = 0; i < 4; ++i)
        #pragma unroll
        for (int j = 0; j < 4; ++j) acc[i][j] = (f32x4){0.f, 0.f, 0.f, 0.f};

    int sr = wid * 32;
    int lr = lane >> 2;
    // staging source column: slot (lane&3) XOR'd with (row>>1)&3 == (lr>>1)&3
    int lc = (((lane & 3) ^ ((lr >> 1) & 3)) * 8);
    int fm = lane & 15;
    int fk = (lane >> 4) * 8;
    // ds_read offset: slot fk/8 XOR'd with (row>>1)&3 == (fm>>1)&3
    int fs = fk ^ (((fm >> 1) & 3) << 3);

    for (int kt = 0; kt < DM / 32; ++kt) {
        int k0 = kt * 32;
        const f16* g0 = Ab + (long)(sr + lr) * DM + k0 + lc;
        async16(g0, &As[sr * 32]);
        async16(g0 + 16 * DM, &As[(sr + 16) * 32]);
        const f16* h0 = Bb + (long)(sr + lr) * DM + k0 + lc;
        async16(h0, &Bs[sr * 32]);
        async16(h0 + 16 * DM, &Bs[(sr + 16) * 32]);
        __syncthreads();

        f16x8 af[4], bfr[4];
        #pragma unroll
        for (int i = 0; i < 4; ++i)
            af[i] = *(const f16x8*)&As[(wm * 64 + i * 16 + fm) * 32 + fs];
        #pragma unroll
        for (int j = 0; j < 4; ++j)
            bfr[j] = *(const f16x8*)&Bs[(wn * 64 + j * 16 + fm) * 32 + fs];
        #pragma unroll
        for (int i = 0; i < 4; ++i)
            #pragma unroll
            for (int j = 0; j < 4; ++j)
                acc[i][j] = __builtin_amdgcn_mfma_f32_16x16x32_f16(af[i], bfr[j], acc[i][j], 0, 0, 0);
        __syncthreads();
    }

    int row0 = (int)rowBase + wm * 64;
    int col0 = cb * 128 + wn * 64;
    #pragma unroll
    for (int j = 0; j < 4; ++j) {
        int c = col0 + j * 16 + (lane & 15);
        float bv = bias[c];
        #pragma unroll
        for (int i = 0; i < 4; ++i) {
            #pragma unroll
            for (int r = 0; r < 4; ++r) {
                int row = row0 + i * 16 + (lane >> 4) * 4 + r;
                if (row < M) {
                    float v = acc[i][j][r] + bv;
                    if (ACT == ACT_RELU) v = v > 0.f ? v : 0.f;
                    if (ACT == ACT_GELU) v = gelu_f(v);
                    C[(long)row * DM + c] = (f16)v;
                }
            }
        }
    }
}

extern "C" void kernel_launch(void* const* d_in, const int* in_sizes, int n_in,
                              void* d_out, int out_size, void* d_ws, size_t ws_size,
                              hipStream_t stream) {
    const int* x  = (const int*)d_in[0];
    const int* ea = (const int*)d_in[1];
    const int* ei = (const int*)d_in[2];
    const float* atom_emb  = (const float*)d_in[3];
    const float* atom_ln_g = (const float*)d_in[4];
    const float* atom_ln_b = (const float*)d_in[5];
    const float* atom_w1   = (const float*)d_in[6];
    const float* atom_b1   = (const float*)d_in[7];
    const float* atom_w2   = (const float*)d_in[8];
    const float* atom_b2   = (const float*)d_in[9];
    const float* bond_emb  = (const float*)d_in[10];
    const float* bond_ln_g = (const float*)d_in[11];
    const float* bond_ln_b = (const float*)d_in[12];
    const float* bond_w1   = (const float*)d_in[13];
    const float* bond_b1   = (const float*)d_in[14];
    const float* bond_w2   = (const float*)d_in[15];
    const float* bond_b2   = (const float*)d_in[16];
    const float* conv_w1   = (const float*)d_in[17];
    const float* conv_b1   = (const float*)d_in[18];
    const float* conv_w2   = (const float*)d_in[19];
    const float* conv_b2   = (const float*)d_in[20];
    const float* ln_g      = (const float*)d_in[21];
    const float* ln_b      = (const float*)d_in[22];

    const int N = in_sizes[0] / 9;
    const int E = in_sizes[1] / 3;
    const int V = in_sizes[10] / (3 * DM);  // bond vocab (8) -> V^3 combos (512)
    const int nC = V * V * V;
    const long SZ = (long)DM * DM;

    // ---- workspace: WT | Q | h | T | key | ids3 (~170 MiB) ----
    char* ws = (char*)d_ws;
    size_t off = 0;
    f16* WT  = (f16*)(ws + off); off += ((size_t)12 * SZ * 2 + 4095) & ~(size_t)4095;
    f16* Q   = (f16*)(ws + off); off += ((size_t)CHUNK * DM * 2 + 4095) & ~(size_t)4095;
    f16* h   = (f16*)(ws + off); off += ((size_t)N * DM * 2 + 4095) & ~(size_t)4095;
    f16* T   = (f16*)(ws + off); off += ((size_t)((nC + 127) & ~127) * DM * 2 + 4095) & ~(size_t)4095;
    int* key = (int*)(ws + off); off += ((size_t)E * 4 + 4095) & ~(size_t)4095;
    int* ids3 = (int*)(ws + off); off += ((size_t)nC * 12 + 4095) & ~(size_t)4095;
    // d_out region (N*DM fp32 = 153.6MB): low half = f16 U scratch (<=76.9MB);
    // head/next parked at +120MB, only clobbered by the final fp32 LN write.
    f16*   U    = (f16*)d_out;
    int*   head = (int*)((char*)d_out + 120000000);
    int*   nxt  = head + N;

    dim3 tb(32, 8), tg(24, 24);
    transpose768<<<tg, tb, 0, stream>>>(atom_w1, WT + 0 * SZ);
    transpose768<<<tg, tb, 0, stream>>>(atom_w2, WT + 1 * SZ);
    transpose768<<<tg, tb, 0, stream>>>(bond_w1, WT + 2 * SZ);
    transpose768<<<tg, tb, 0, stream>>>(bond_w2, WT + 3 * SZ);
    for (int l = 0; l < NLAYERS; ++l) {
        transpose768<<<tg, tb, 0, stream>>>(conv_w1 + l * SZ, WT + (4 + l) * SZ);
        transpose768<<<tg, tb, 0, stream>>>(conv_w2 + l * SZ, WT + (8 + l) * SZ);
    }

    // build dst->edges linked list + per-edge combo key (edge data is constant)
    hipMemsetAsync(head, 0xFF, (size_t)N * 4, stream);  // head = -1
    build_list_kernel<<<(E + 255) / 256, 256, 0, stream>>>(ei, E, head, nxt);
    make_key_kernel<<<(E + 255) / 256, 256, 0, stream>>>(ea, E, V, key);

    int rtN = (N + 127) / 128;
    dim3 gn(6 * rtN);   // 1-D, XCD-chunked swizzle inside the kernel

    // AtomEncoder: h = gelu(LN(sum emb) @ w1 + b1) @ w2 + b2   (Q -> U(d_out) -> h)
    embed_ln_kernel<<<N, 256, 0, stream>>>(x, 9, 128, atom_emb, atom_ln_g, atom_ln_b, Q);
    gemm768<ACT_GELU><<<gn, 256, 0, stream>>>(Q, WT + 0 * SZ, atom_b1, U, N);
    gemm768<ACT_NONE><<<gn, 256, 0, stream>>>(U, WT + 1 * SZ, atom_b2, h, N);

    // BondEncoder on the V^3 combo table only: Q -> U(d_out) -> T
    make_combo_ids<<<(nC + 255) / 256, 256, 0, stream>>>(V, nC, ids3);
    embed_ln_kernel<<<nC, 256, 0, stream>>>(ids3, 3, V, bond_emb, bond_ln_g, bond_ln_b, Q);
    dim3 gt(6 * ((nC + 127) / 128));
    gemm768<ACT_GELU><<<gt, 256, 0, stream>>>(Q, WT + 2 * SZ, bond_b1, U, nC);
    gemm768<ACT_NONE><<<gt, 256, 0, stream>>>(U, WT + 3 * SZ, bond_b2, T, nC);

    for (int l = 0; l < NLAYERS; ++l) {
        // z = h + sum_{j->i} relu(h[src] + T[key])  -> Q (f16), pure gather
        gather_agg_kernel<<<(N + 3) / 4, 256, 0, stream>>>(ei, head, nxt, key, h, T, Q, N);
        gemm768<ACT_RELU><<<gn, 256, 0, stream>>>(Q, WT + (4 + l) * SZ, conv_b1 + l * DM, U, N);  // U -> d_out
        gemm768<ACT_NONE><<<gn, 256, 0, stream>>>(U, WT + (8 + l) * SZ, conv_b2 + l * DM, Q, N);  // V -> Q
        if (l == NLAYERS - 1) {
            gelu_res_ln_kernel<float><<<N, 256, 0, stream>>>(Q, h, ln_g + l * DM, ln_b + l * DM, (float*)d_out);
        } else {
            gelu_res_ln_kernel<f16><<<N, 256, 0, stream>>>(Q, h, ln_g + l * DM, ln_b + l * DM, h);
        }
    }
}

// Round 5
// 1676.046 us; speedup vs baseline: 3.9000x; 1.1220x over previous
//
#include <hip/hip_runtime.h>

// GraphEncoder: GINE-style GNN, D=768, 4 layers. fp32 I/O, f16 intermediates +
// f16 MFMA GEMMs, fp32 accumulate/LN/scatter math.
//
// Round 7: GEMM epilogue rewrite via MFMA operand swap. Old layout stored 64x
// 2-byte global_store_short per thread (~38M store instrs/dispatch ~= 62us of
// issue, + ~1.9x HBM write amplification; round-6 counters: WRITE 146MB vs
// 77MB ideal). A/B fragments share the same lane addressing, so
// mfma(bfr, af, acc) transposes the D mapping: C-row = lane&15 (fixed),
// C-col = (lane>>4)*4 + r (consecutive) -> one f16x4 8B store per reg quad
// (16 stores/thread, 4x wider), bias loaded as aligned float4.
//
// Kept from earlier rounds: XCD-chunked 1-D grid swizzle (FETCH 238->54MB),
// LDS XOR-swizzle (bank-conflict-free), deduped bond encoder (512-combo
// table), linked-list gather aggregation (no float atomics).
//
// Workspace: [WT 12x768x768 f16 | Q 50048x768 f16 | h Nx768 f16 | T | key | ids3]
// d_out (Nx768 fp32, 153.6MB): low half = f16 U scratch; head/next parked at
// +120MB (clobbered only by the final fp32 LN write, which covers all of d_out).

#define DM 768
#define NLAYERS 4
#define CHUNK 50048  // row capacity for Q (multiple of 128, >= N)

typedef _Float16 f16;
typedef __attribute__((ext_vector_type(8))) _Float16 f16x8;
typedef __attribute__((ext_vector_type(4))) _Float16 f16x4;
typedef __attribute__((ext_vector_type(4))) float f32x4;

__device__ __forceinline__ float gelu_f(float x) {
    float x3 = x * x * x;
    return 0.5f * x * (1.0f + tanhf(0.7978845608028654f * (x + 0.044715f * x3)));
}
__device__ __forceinline__ void async16(const void* g, void* l) {
    __builtin_amdgcn_global_load_lds((const __attribute__((address_space(1))) void*)g,
                                     (__attribute__((address_space(3))) void*)l,
                                     16, 0, 0);
}

// bijective XCD-chunked swizzle (m204): XCD k = b%8 gets a contiguous range of
// work ids; within the range, original b/8 order is preserved.
__device__ __forceinline__ int xcd_swizzle(int b, int nb) {
    int xcd = b & 7;
    int pos = b >> 3;
    int q = nb >> 3, r = nb & 7;
    int base = (xcd < r) ? xcd * (q + 1) : r * (q + 1) + (xcd - r) * q;
    return base + pos;
}

__device__ __forceinline__ void block_reduce2(float& s1, float& s2, float* sm) {
    #pragma unroll
    for (int off = 32; off > 0; off >>= 1) {
        s1 += __shfl_down(s1, off);
        s2 += __shfl_down(s2, off);
    }
    int lane = threadIdx.x & 63, wid = threadIdx.x >> 6;
    if (lane == 0) { sm[wid * 2] = s1; sm[wid * 2 + 1] = s2; }
    __syncthreads();
    s1 = sm[0] + sm[2] + sm[4] + sm[6];
    s2 = sm[1] + sm[3] + sm[5] + sm[7];
}

// -------- weight transpose + fp32->fp16: Wt[n][k] = W[k][n], 768x768 ----------
__global__ __launch_bounds__(256) void transpose768(
    const float* __restrict__ W, f16* __restrict__ Wt) {
    __shared__ float t[32][33];
    int tx = threadIdx.x, ty = threadIdx.y;
    int c0 = blockIdx.x * 32, r0 = blockIdx.y * 32;
    #pragma unroll
    for (int j = 0; j < 32; j += 8) t[ty + j][tx] = W[(r0 + ty + j) * DM + c0 + tx];
    __syncthreads();
    #pragma unroll
    for (int j = 0; j < 32; j += 8) Wt[(long)(c0 + ty + j) * DM + r0 + tx] = (f16)t[tx][ty + j];
}

// -------- embedding-sum + LayerNorm (encoder front), fp32 in, fp16 out ----------
__global__ __launch_bounds__(256) void embed_ln_kernel(
    const int* __restrict__ ids, int F, int V,
    const float* __restrict__ emb,
    const float* __restrict__ g, const float* __restrict__ b,
    f16* __restrict__ out) {
    int m = blockIdx.x, tid = threadIdx.x;
    float v[3] = {0.f, 0.f, 0.f};
    for (int f = 0; f < F; ++f) {
        int id = ids[(long)m * F + f];
        const float* row = emb + ((long)f * V + id) * DM;
        v[0] += row[tid];
        v[1] += row[tid + 256];
        v[2] += row[tid + 512];
    }
    float s1 = v[0] + v[1] + v[2];
    float s2 = v[0] * v[0] + v[1] * v[1] + v[2] * v[2];
    __shared__ float sm[8];
    block_reduce2(s1, s2, sm);
    float mean = s1 * (1.f / DM);
    float var = s2 * (1.f / DM) - mean * mean;
    float rstd = rsqrtf(var + 1e-5f);
    #pragma unroll
    for (int q = 0; q < 3; ++q) {
        int d = tid + q * 256;
        out[(long)m * DM + d] = (f16)((v[q] - mean) * rstd * g[d] + b[d]);
    }
}

// -------- gelu(U) + h_in -> LayerNorm -> out ----------
template <typename OUT>
__global__ __launch_bounds__(256) void gelu_res_ln_kernel(
    const f16* __restrict__ U, const f16* __restrict__ hin,
    const float* __restrict__ g, const float* __restrict__ b,
    OUT* __restrict__ out) {
    int m = blockIdx.x, tid = threadIdx.x;
    float v[3];
    #pragma unroll
    for (int q = 0; q < 3; ++q) {
        int d = tid + q * 256;
        v[q] = gelu_f((float)U[(long)m * DM + d]) + (float)hin[(long)m * DM + d];
    }
    float s1 = v[0] + v[1] + v[2];
    float s2 = v[0] * v[0] + v[1] * v[1] + v[2] * v[2];
    __shared__ float sm[8];
    block_reduce2(s1, s2, sm);
    float mean = s1 * (1.f / DM);
    float var = s2 * (1.f / DM) - mean * mean;
    float rstd = rsqrtf(var + 1e-5f);
    #pragma unroll
    for (int q = 0; q < 3; ++q) {
        int d = tid + q * 256;
        out[(long)m * DM + d] = (OUT)((v[q] - mean) * rstd * g[d] + b[d]);
    }
}

// -------- bond-combo helpers: ids for all V^3 combos; per-edge key ----------
__global__ __launch_bounds__(256) void make_combo_ids(
    int V, int nC, int* __restrict__ ids) {
    int c = blockIdx.x * 256 + threadIdx.x;
    if (c >= nC) return;
    ids[c * 3 + 0] = c / (V * V);
    ids[c * 3 + 1] = (c / V) % V;
    ids[c * 3 + 2] = c % V;
}
__global__ __launch_bounds__(256) void make_key_kernel(
    const int* __restrict__ ea, int E, int V, int* __restrict__ key) {
    int e = blockIdx.x * 256 + threadIdx.x;
    if (e >= E) return;
    key[e] = (ea[e * 3 + 0] * V + ea[e * 3 + 1]) * V + ea[e * 3 + 2];
}

// -------- build per-dst edge linked list (once; edge_index is layer-invariant) --
__global__ __launch_bounds__(256) void build_list_kernel(
    const int* __restrict__ ei, int E,
    int* __restrict__ head, int* __restrict__ nxt) {
    int e = blockIdx.x * 256 + threadIdx.x;
    if (e >= E) return;
    int dst = ei[E + e];
    nxt[e] = atomicExch(&head[dst], e);  // device-scope; order irrelevant (sum)
}

// -------- per-node gather aggregation: z[n] = h[n] + sum relu(h[src]+T[key]) --
// One wave per node; wave-uniform list walk (no divergence). 12 f16/lane.
// fp32 in-register accumulate. Edge features come from the 512-row combo
// table T (L2-resident) via key[edge].
__global__ __launch_bounds__(256) void gather_agg_kernel(
    const int* __restrict__ ei,
    const int* __restrict__ head, const int* __restrict__ nxt,
    const int* __restrict__ key,
    const f16* __restrict__ h, const f16* __restrict__ T,
    f16* __restrict__ z, int N) {
    int node = blockIdx.x * 4 + (threadIdx.x >> 6);
    if (node >= N) return;
    int lane = threadIdx.x & 63;
    int base = lane * 12;

    const f16* hr = h + (long)node * DM + base;
    f16x4 v0 = *(const f16x4*)&hr[0];
    f16x4 v1 = *(const f16x4*)&hr[4];
    f16x4 v2 = *(const f16x4*)&hr[8];
    float acc[12];
    #pragma unroll
    for (int j = 0; j < 4; ++j) {
        acc[j]     = (float)v0[j];
        acc[4 + j] = (float)v1[j];
        acc[8 + j] = (float)v2[j];
    }

    int ecur = head[node];
    while (ecur >= 0) {
        int enext = nxt[ecur];          // issue chase early; rows overlap it
        int src = ei[ecur];
        int kq = key[ecur];
        const f16* sr = h + (long)src * DM + base;
        const f16* er = T + (long)kq * DM + base;
        f16x4 a0 = *(const f16x4*)&sr[0];
        f16x4 a1 = *(const f16x4*)&sr[4];
        f16x4 a2 = *(const f16x4*)&sr[8];
        f16x4 b0 = *(const f16x4*)&er[0];
        f16x4 b1 = *(const f16x4*)&er[4];
        f16x4 b2 = *(const f16x4*)&er[8];
        #pragma unroll
        for (int j = 0; j < 4; ++j) {
            float m0 = (float)a0[j] + (float)b0[j];
            float m1 = (float)a1[j] + (float)b1[j];
            float m2 = (float)a2[j] + (float)b2[j];
            if (m0 > 0.f) acc[j]     += m0;
            if (m1 > 0.f) acc[4 + j] += m1;
            if (m2 > 0.f) acc[8 + j] += m2;
        }
        ecur = enext;
    }

    f16* zr = z + (long)node * DM + base;
    f16x4 o0, o1, o2;
    #pragma unroll
    for (int j = 0; j < 4; ++j) {
        o0[j] = (f16)acc[j];
        o1[j] = (f16)acc[4 + j];
        o2[j] = (f16)acc[8 + j];
    }
    *(f16x4*)&zr[0] = o0;
    *(f16x4*)&zr[4] = o1;
    *(f16x4*)&zr[8] = o2;
}

// -------- GEMM: C[M,768] = act(A[M,768] @ W + bias), Bt[n][k] = W[k][n] ----------
// 1-D grid, XCD-chunked swizzle (col-fastest within an XCD's chunk).
// MFMA operands SWAPPED: mfma(bfr, af, acc) -> D is the transposed sub-tile,
// so per lane C-row = lane&15 (fixed) and C-col = (lane>>4)*4 + r
// (consecutive) -> 8B f16x4 stores, bias as aligned float4.
// LDS tiles [128][32] f16 XOR-swizzled both-sides (rule #21).
#define ACT_NONE 0
#define ACT_RELU 1
#define ACT_GELU 2

template <int ACT>
__global__ __launch_bounds__(256, 2) void gemm768(
    const f16* __restrict__ A,      // [M,768] f16; rows may overread <=127 past M (mapped)
    const f16* __restrict__ Bt,     // [768,768] f16, Bt[n][k] = W[k][n]
    const float* __restrict__ bias, // [768] fp32
    f16* __restrict__ C,            // [M,768] f16
    int M) {
    __shared__ f16 As[128 * 32];
    __shared__ f16 Bs[128 * 32];
    int tid = threadIdx.x;
    int lane = tid & 63;
    int wid = tid >> 6;
    int wm = wid >> 1, wn = wid & 1;

    int wg = xcd_swizzle(blockIdx.x, gridDim.x);
    int rt = wg / 6, cb = wg - rt * 6;
    long rowBase = (long)rt * 128;
    const f16* Ab = A + rowBase * DM;
    const f16* Bb = Bt + (long)cb * 128 * DM;

    f32x4 acc[4][4];  // acc[ci][ri]: ci = col subtile (from Bt), ri = row subtile
    #pragma unroll
    for (int i = 0; i < 4; ++i)
        #pragma unroll
        for (int j = 0; j < 4; ++j) acc[i][j] = (f32x4){0.f, 0.f, 0.f, 0.f};

    int sr = wid * 32;
    int lr = lane >> 2;
    // staging source column: slot (lane&3) XOR'd with (row>>1)&3 == (lr>>1)&3
    int lc = (((lane & 3) ^ ((lr >> 1) & 3)) * 8);
    int fm = lane & 15;
    int fk = (lane >> 4) * 8;
    // ds_read offset: slot fk/8 XOR'd with (row>>1)&3 == (fm>>1)&3
    int fs = fk ^ (((fm >> 1) & 3) << 3);

    for (int kt = 0; kt < DM / 32; ++kt) {
        int k0 = kt * 32;
        const f16* g0 = Ab + (long)(sr + lr) * DM + k0 + lc;
        async16(g0, &As[sr * 32]);
        async16(g0 + 16 * DM, &As[(sr + 16) * 32]);
        const f16* h0 = Bb + (long)(sr + lr) * DM + k0 + lc;
        async16(h0, &Bs[sr * 32]);
        async16(h0 + 16 * DM, &Bs[(sr + 16) * 32]);
        __syncthreads();

        f16x8 af[4], bfr[4];
        #pragma unroll
        for (int i = 0; i < 4; ++i)
            af[i] = *(const f16x8*)&As[(wm * 64 + i * 16 + fm) * 32 + fs];
        #pragma unroll
        for (int j = 0; j < 4; ++j)
            bfr[j] = *(const f16x8*)&Bs[(wn * 64 + j * 16 + fm) * 32 + fs];
        #pragma unroll
        for (int ci = 0; ci < 4; ++ci)
            #pragma unroll
            for (int ri = 0; ri < 4; ++ri)
                acc[ci][ri] = __builtin_amdgcn_mfma_f32_16x16x32_f16(bfr[ci], af[ri], acc[ci][ri], 0, 0, 0);
        __syncthreads();
    }

    int row0 = (int)rowBase + wm * 64;
    int col0 = cb * 128 + wn * 64;
    // bias: 4 consecutive cols per (ci), 16B-aligned
    float4 bv[4];
    #pragma unroll
    for (int ci = 0; ci < 4; ++ci)
        bv[ci] = *(const float4*)&bias[col0 + ci * 16 + (lane >> 4) * 4];
    #pragma unroll
    for (int ri = 0; ri < 4; ++ri) {
        int row = row0 + ri * 16 + (lane & 15);
        if (row < M) {
            #pragma unroll
            for (int ci = 0; ci < 4; ++ci) {
                int c0 = col0 + ci * 16 + (lane >> 4) * 4;
                f16x4 o;
                #pragma unroll
                for (int r = 0; r < 4; ++r) {
                    float v = acc[ci][ri][r] + (&bv[ci].x)[r];
                    if (ACT == ACT_RELU) v = v > 0.f ? v : 0.f;
                    if (ACT == ACT_GELU) v = gelu_f(v);
                    o[r] = (f16)v;
                }
                *(f16x4*)&C[(long)row * DM + c0] = o;
            }
        }
    }
}

extern "C" void kernel_launch(void* const* d_in, const int* in_sizes, int n_in,
                              void* d_out, int out_size, void* d_ws, size_t ws_size,
                              hipStream_t stream) {
    const int* x  = (const int*)d_in[0];
    const int* ea = (const int*)d_in[1];
    const int* ei = (const int*)d_in[2];
    const float* atom_emb  = (const float*)d_in[3];
    const float* atom_ln_g = (const float*)d_in[4];
    const float* atom_ln_b = (const float*)d_in[5];
    const float* atom_w1   = (const float*)d_in[6];
    const float* atom_b1   = (const float*)d_in[7];
    const float* atom_w2   = (const float*)d_in[8];
    const float* atom_b2   = (const float*)d_in[9];
    const float* bond_emb  = (const float*)d_in[10];
    const float* bond_ln_g = (const float*)d_in[11];
    const float* bond_ln_b = (const float*)d_in[12];
    const float* bond_w1   = (const float*)d_in[13];
    const float* bond_b1   = (const float*)d_in[14];
    const float* bond_w2   = (const float*)d_in[15];
    const float* bond_b2   = (const float*)d_in[16];
    const float* conv_w1   = (const float*)d_in[17];
    const float* conv_b1   = (const float*)d_in[18];
    const float* conv_w2   = (const float*)d_in[19];
    const float* conv_b2   = (const float*)d_in[20];
    const float* ln_g      = (const float*)d_in[21];
    const float* ln_b      = (const float*)d_in[22];

    const int N = in_sizes[0] / 9;
    const int E = in_sizes[1] / 3;
    const int V = in_sizes[10] / (3 * DM);  // bond vocab (8) -> V^3 combos (512)
    const int nC = V * V * V;
    const long SZ = (long)DM * DM;

    // ---- workspace: WT | Q | h | T | key | ids3 (~170 MiB) ----
    char* ws = (char*)d_ws;
    size_t off = 0;
    f16* WT  = (f16*)(ws + off); off += ((size_t)12 * SZ * 2 + 4095) & ~(size_t)4095;
    f16* Q   = (f16*)(ws + off); off += ((size_t)CHUNK * DM * 2 + 4095) & ~(size_t)4095;
    f16* h   = (f16*)(ws + off); off += ((size_t)N * DM * 2 + 4095) & ~(size_t)4095;
    f16* T   = (f16*)(ws + off); off += ((size_t)((nC + 127) & ~127) * DM * 2 + 4095) & ~(size_t)4095;
    int* key = (int*)(ws + off); off += ((size_t)E * 4 + 4095) & ~(size_t)4095;
    int* ids3 = (int*)(ws + off); off += ((size_t)nC * 12 + 4095) & ~(size_t)4095;
    // d_out region (N*DM fp32 = 153.6MB): low half = f16 U scratch (<=76.9MB);
    // head/next parked at +120MB, only clobbered by the final fp32 LN write.
    f16*   U    = (f16*)d_out;
    int*   head = (int*)((char*)d_out + 120000000);
    int*   nxt  = head + N;

    dim3 tb(32, 8), tg(24, 24);
    transpose768<<<tg, tb, 0, stream>>>(atom_w1, WT + 0 * SZ);
    transpose768<<<tg, tb, 0, stream>>>(atom_w2, WT + 1 * SZ);
    transpose768<<<tg, tb, 0, stream>>>(bond_w1, WT + 2 * SZ);
    transpose768<<<tg, tb, 0, stream>>>(bond_w2, WT + 3 * SZ);
    for (int l = 0; l < NLAYERS; ++l) {
        transpose768<<<tg, tb, 0, stream>>>(conv_w1 + l * SZ, WT + (4 + l) * SZ);
        transpose768<<<tg, tb, 0, stream>>>(conv_w2 + l * SZ, WT + (8 + l) * SZ);
    }

    // build dst->edges linked list + per-edge combo key (edge data is constant)
    hipMemsetAsync(head, 0xFF, (size_t)N * 4, stream);  // head = -1
    build_list_kernel<<<(E + 255) / 256, 256, 0, stream>>>(ei, E, head, nxt);
    make_key_kernel<<<(E + 255) / 256, 256, 0, stream>>>(ea, E, V, key);

    int rtN = (N + 127) / 128;
    dim3 gn(6 * rtN);   // 1-D, XCD-chunked swizzle inside the kernel

    // AtomEncoder: h = gelu(LN(sum emb) @ w1 + b1) @ w2 + b2   (Q -> U(d_out) -> h)
    embed_ln_kernel<<<N, 256, 0, stream>>>(x, 9, 128, atom_emb, atom_ln_g, atom_ln_b, Q);
    gemm768<ACT_GELU><<<gn, 256, 0, stream>>>(Q, WT + 0 * SZ, atom_b1, U, N);
    gemm768<ACT_NONE><<<gn, 256, 0, stream>>>(U, WT + 1 * SZ, atom_b2, h, N);

    // BondEncoder on the V^3 combo table only: Q -> U(d_out) -> T
    make_combo_ids<<<(nC + 255) / 256, 256, 0, stream>>>(V, nC, ids3);
    embed_ln_kernel<<<nC, 256, 0, stream>>>(ids3, 3, V, bond_emb, bond_ln_g, bond_ln_b, Q);
    dim3 gt(6 * ((nC + 127) / 128));
    gemm768<ACT_GELU><<<gt, 256, 0, stream>>>(Q, WT + 2 * SZ, bond_b1, U, nC);
    gemm768<ACT_NONE><<<gt, 256, 0, stream>>>(U, WT + 3 * SZ, bond_b2, T, nC);

    for (int l = 0; l < NLAYERS; ++l) {
        // z = h + sum_{j->i} relu(h[src] + T[key])  -> Q (f16), pure gather
        gather_agg_kernel<<<(N + 3) / 4, 256, 0, stream>>>(ei, head, nxt, key, h, T, Q, N);
        gemm768<ACT_RELU><<<gn, 256, 0, stream>>>(Q, WT + (4 + l) * SZ, conv_b1 + l * DM, U, N);  // U -> d_out
        gemm768<ACT_NONE><<<gn, 256, 0, stream>>>(U, WT + (8 + l) * SZ, conv_b2 + l * DM, Q, N);  // V -> Q
        if (l == NLAYERS - 1) {
            gelu_res_ln_kernel<float><<<N, 256, 0, stream>>>(Q, h, ln_g + l * DM, ln_b + l * DM, (float*)d_out);
        } else {
            gelu_res_ln_kernel<f16><<<N, 256, 0, stream>>>(Q, h, ln_g + l * DM, ln_b + l * DM, h);
        }
    }
}

// Round 6
// 1610.033 us; speedup vs baseline: 4.0599x; 1.0410x over previous
//
#include <hip/hip_runtime.h>

// GraphEncoder: GINE-style GNN, D=768, 4 layers. fp32 I/O, f16 intermediates +
// f16 MFMA GEMMs, fp32 accumulate/LN/scatter math.
//
// Round 8:
//  - GEMM K-loop -> T3 minimal 2-phase pipeline: double-buffered LDS, next
//    tile's global_load_lds issued BEFORE computing current tile, raw
//    s_barrier + counted vmcnt(4) (NOT the compiler's vmcnt(0) drain) so
//    prefetch loads stay in flight across the barrier. Kills the ~200-300cyc
//    per-K-iter latency exposure of the single-buffer 2-barrier structure
//    (round-7 counters: MfmaUtil 23%, HBM 15% -> latency/issue-bound).
//  - gelu via __expf-based tanh (saturating), replacing the tanhf libcall
//    (GELU GEMM was the slowest variant; gelu_res_ln x4 pays it too).
//
// Kept: operand-swapped MFMA epilogue (8B f16x4 C stores, WRITE=ideal 77MB),
// XCD-chunked 1-D grid swizzle (FETCH 238->54MB), LDS XOR-swizzle
// (bank-conflict-free), deduped bond encoder (512-combo table), linked-list
// gather aggregation (no float atomics).
//
// Workspace: [WT 12x768x768 f16 | Q 50048x768 f16 | h Nx768 f16 | T | key | ids3]
// d_out (Nx768 fp32, 153.6MB): low half = f16 U scratch; head/next parked at
// +120MB (clobbered only by the final fp32 LN write, which covers all of d_out).

#define DM 768
#define NLAYERS 4
#define CHUNK 50048  // row capacity for Q (multiple of 128, >= N)

typedef _Float16 f16;
typedef __attribute__((ext_vector_type(8))) _Float16 f16x8;
typedef __attribute__((ext_vector_type(4))) _Float16 f16x4;
typedef __attribute__((ext_vector_type(4))) float f32x4;

// gelu(x) = 0.5x(1+tanh(0.79788456(x+0.044715x^3))), tanh via exp:
// tanh(u) = sign(u) * (1 - a)/(1 + a), a = exp(-2|u|)  (a->0 saturates cleanly)
__device__ __forceinline__ float gelu_f(float x) {
    float u = 0.7978845608028654f * (x + 0.044715f * x * x * x);
    float a = __expf(-2.0f * fabsf(u));
    float t = (1.0f - a) / (1.0f + a);
    t = copysignf(t, u);
    return 0.5f * x * (1.0f + t);
}
__device__ __forceinline__ void async16(const void* g, void* l) {
    __builtin_amdgcn_global_load_lds((const __attribute__((address_space(1))) void*)g,
                                     (__attribute__((address_space(3))) void*)l,
                                     16, 0, 0);
}

// bijective XCD-chunked swizzle (m204): XCD k = b%8 gets a contiguous range of
// work ids; within the range, original b/8 order is preserved.
__device__ __forceinline__ int xcd_swizzle(int b, int nb) {
    int xcd = b & 7;
    int pos = b >> 3;
    int q = nb >> 3, r = nb & 7;
    int base = (xcd < r) ? xcd * (q + 1) : r * (q + 1) + (xcd - r) * q;
    return base + pos;
}

__device__ __forceinline__ void block_reduce2(float& s1, float& s2, float* sm) {
    #pragma unroll
    for (int off = 32; off > 0; off >>= 1) {
        s1 += __shfl_down(s1, off);
        s2 += __shfl_down(s2, off);
    }
    int lane = threadIdx.x & 63, wid = threadIdx.x >> 6;
    if (lane == 0) { sm[wid * 2] = s1; sm[wid * 2 + 1] = s2; }
    __syncthreads();
    s1 = sm[0] + sm[2] + sm[4] + sm[6];
    s2 = sm[1] + sm[3] + sm[5] + sm[7];
}

// -------- weight transpose + fp32->fp16: Wt[n][k] = W[k][n], 768x768 ----------
__global__ __launch_bounds__(256) void transpose768(
    const float* __restrict__ W, f16* __restrict__ Wt) {
    __shared__ float t[32][33];
    int tx = threadIdx.x, ty = threadIdx.y;
    int c0 = blockIdx.x * 32, r0 = blockIdx.y * 32;
    #pragma unroll
    for (int j = 0; j < 32; j += 8) t[ty + j][tx] = W[(r0 + ty + j) * DM + c0 + tx];
    __syncthreads();
    #pragma unroll
    for (int j = 0; j < 32; j += 8) Wt[(long)(c0 + ty + j) * DM + r0 + tx] = (f16)t[tx][ty + j];
}

// -------- embedding-sum + LayerNorm (encoder front), fp32 in, fp16 out ----------
__global__ __launch_bounds__(256) void embed_ln_kernel(
    const int* __restrict__ ids, int F, int V,
    const float* __restrict__ emb,
    const float* __restrict__ g, const float* __restrict__ b,
    f16* __restrict__ out) {
    int m = blockIdx.x, tid = threadIdx.x;
    float v[3] = {0.f, 0.f, 0.f};
    for (int f = 0; f < F; ++f) {
        int id = ids[(long)m * F + f];
        const float* row = emb + ((long)f * V + id) * DM;
        v[0] += row[tid];
        v[1] += row[tid + 256];
        v[2] += row[tid + 512];
    }
    float s1 = v[0] + v[1] + v[2];
    float s2 = v[0] * v[0] + v[1] * v[1] + v[2] * v[2];
    __shared__ float sm[8];
    block_reduce2(s1, s2, sm);
    float mean = s1 * (1.f / DM);
    float var = s2 * (1.f / DM) - mean * mean;
    float rstd = rsqrtf(var + 1e-5f);
    #pragma unroll
    for (int q = 0; q < 3; ++q) {
        int d = tid + q * 256;
        out[(long)m * DM + d] = (f16)((v[q] - mean) * rstd * g[d] + b[d]);
    }
}

// -------- gelu(U) + h_in -> LayerNorm -> out ----------
template <typename OUT>
__global__ __launch_bounds__(256) void gelu_res_ln_kernel(
    const f16* __restrict__ U, const f16* __restrict__ hin,
    const float* __restrict__ g, const float* __restrict__ b,
    OUT* __restrict__ out) {
    int m = blockIdx.x, tid = threadIdx.x;
    float v[3];
    #pragma unroll
    for (int q = 0; q < 3; ++q) {
        int d = tid + q * 256;
        v[q] = gelu_f((float)U[(long)m * DM + d]) + (float)hin[(long)m * DM + d];
    }
    float s1 = v[0] + v[1] + v[2];
    float s2 = v[0] * v[0] + v[1] * v[1] + v[2] * v[2];
    __shared__ float sm[8];
    block_reduce2(s1, s2, sm);
    float mean = s1 * (1.f / DM);
    float var = s2 * (1.f / DM) - mean * mean;
    float rstd = rsqrtf(var + 1e-5f);
    #pragma unroll
    for (int q = 0; q < 3; ++q) {
        int d = tid + q * 256;
        out[(long)m * DM + d] = (OUT)((v[q] - mean) * rstd * g[d] + b[d]);
    }
}

// -------- bond-combo helpers: ids for all V^3 combos; per-edge key ----------
__global__ __launch_bounds__(256) void make_combo_ids(
    int V, int nC, int* __restrict__ ids) {
    int c = blockIdx.x * 256 + threadIdx.x;
    if (c >= nC) return;
    ids[c * 3 + 0] = c / (V * V);
    ids[c * 3 + 1] = (c / V) % V;
    ids[c * 3 + 2] = c % V;
}
__global__ __launch_bounds__(256) void make_key_kernel(
    const int* __restrict__ ea, int E, int V, int* __restrict__ key) {
    int e = blockIdx.x * 256 + threadIdx.x;
    if (e >= E) return;
    key[e] = (ea[e * 3 + 0] * V + ea[e * 3 + 1]) * V + ea[e * 3 + 2];
}

// -------- build per-dst edge linked list (once; edge_index is layer-invariant) --
__global__ __launch_bounds__(256) void build_list_kernel(
    const int* __restrict__ ei, int E,
    int* __restrict__ head, int* __restrict__ nxt) {
    int e = blockIdx.x * 256 + threadIdx.x;
    if (e >= E) return;
    int dst = ei[E + e];
    nxt[e] = atomicExch(&head[dst], e);  // device-scope; order irrelevant (sum)
}

// -------- per-node gather aggregation: z[n] = h[n] + sum relu(h[src]+T[key]) --
// One wave per node; wave-uniform list walk (no divergence). 12 f16/lane.
// fp32 in-register accumulate. Edge features come from the 512-row combo
// table T (L2-resident) via key[edge].
__global__ __launch_bounds__(256) void gather_agg_kernel(
    const int* __restrict__ ei,
    const int* __restrict__ head, const int* __restrict__ nxt,
    const int* __restrict__ key,
    const f16* __restrict__ h, const f16* __restrict__ T,
    f16* __restrict__ z, int N) {
    int node = blockIdx.x * 4 + (threadIdx.x >> 6);
    if (node >= N) return;
    int lane = threadIdx.x & 63;
    int base = lane * 12;

    const f16* hr = h + (long)node * DM + base;
    f16x4 v0 = *(const f16x4*)&hr[0];
    f16x4 v1 = *(const f16x4*)&hr[4];
    f16x4 v2 = *(const f16x4*)&hr[8];
    float acc[12];
    #pragma unroll
    for (int j = 0; j < 4; ++j) {
        acc[j]     = (float)v0[j];
        acc[4 + j] = (float)v1[j];
        acc[8 + j] = (float)v2[j];
    }

    int ecur = head[node];
    while (ecur >= 0) {
        int enext = nxt[ecur];          // issue chase early; rows overlap it
        int src = ei[ecur];
        int kq = key[ecur];
        const f16* sr = h + (long)src * DM + base;
        const f16* er = T + (long)kq * DM + base;
        f16x4 a0 = *(const f16x4*)&sr[0];
        f16x4 a1 = *(const f16x4*)&sr[4];
        f16x4 a2 = *(const f16x4*)&sr[8];
        f16x4 b0 = *(const f16x4*)&er[0];
        f16x4 b1 = *(const f16x4*)&er[4];
        f16x4 b2 = *(const f16x4*)&er[8];
        #pragma unroll
        for (int j = 0; j < 4; ++j) {
            float m0 = (float)a0[j] + (float)b0[j];
            float m1 = (float)a1[j] + (float)b1[j];
            float m2 = (float)a2[j] + (float)b2[j];
            if (m0 > 0.f) acc[j]     += m0;
            if (m1 > 0.f) acc[4 + j] += m1;
            if (m2 > 0.f) acc[8 + j] += m2;
        }
        ecur = enext;
    }

    f16* zr = z + (long)node * DM + base;
    f16x4 o0, o1, o2;
    #pragma unroll
    for (int j = 0; j < 4; ++j) {
        o0[j] = (f16)acc[j];
        o1[j] = (f16)acc[4 + j];
        o2[j] = (f16)acc[8 + j];
    }
    *(f16x4*)&zr[0] = o0;
    *(f16x4*)&zr[4] = o1;
    *(f16x4*)&zr[8] = o2;
}

// -------- GEMM: C[M,768] = act(A[M,768] @ W + bias), Bt[n][k] = W[k][n] ----------
// 1-D grid, XCD-chunked swizzle. MFMA operands swapped (transposed D) for 8B
// f16x4 C stores. 2-phase pipeline: LDS double-buffer, prefetch next K-tile
// before computing current, raw s_barrier + counted vmcnt(4) so the 4 in-flight
// prefetch loads are NOT drained at the barrier (T3 minimum recipe).
// LDS tiles [128][32] f16 XOR-swizzled both-sides (rule #21).
#define ACT_NONE 0
#define ACT_RELU 1
#define ACT_GELU 2

template <int ACT>
__global__ __launch_bounds__(256, 2) void gemm768(
    const f16* __restrict__ A,      // [M,768] f16; rows may overread <=127 past M (mapped)
    const f16* __restrict__ Bt,     // [768,768] f16, Bt[n][k] = W[k][n]
    const float* __restrict__ bias, // [768] fp32
    f16* __restrict__ C,            // [M,768] f16
    int M) {
    __shared__ f16 As[2][128 * 32];
    __shared__ f16 Bs[2][128 * 32];
    int tid = threadIdx.x;
    int lane = tid & 63;
    int wid = tid >> 6;
    int wm = wid >> 1, wn = wid & 1;

    int wg = xcd_swizzle(blockIdx.x, gridDim.x);
    int rt = wg / 6, cb = wg - rt * 6;
    long rowBase = (long)rt * 128;
    const f16* Ab = A + rowBase * DM;
    const f16* Bb = Bt + (long)cb * 128 * DM;

    f32x4 acc[4][4];  // acc[ci][ri]: ci = col subtile (from Bt), ri = row subtile
    #pragma unroll
    for (int i = 0; i < 4; ++i)
        #pragma unroll
        for (int j = 0; j < 4; ++j) acc[i][j] = (f32x4){0.f, 0.f, 0.f, 0.f};

    int sr = wid * 32;
    int lr = lane >> 2;
    // staging source column: slot (lane&3) XOR'd with (row>>1)&3 == (lr>>1)&3
    int lc = (((lane & 3) ^ ((lr >> 1) & 3)) * 8);
    int fm = lane & 15;
    int fk = (lane >> 4) * 8;
    // ds_read offset: slot fk/8 XOR'd with (row>>1)&3 == (fm>>1)&3
    int fs = fk ^ (((fm >> 1) & 3) << 3);

    const f16* ap = Ab + (long)(sr + lr) * DM + lc;
    const f16* bp = Bb + (long)(sr + lr) * DM + lc;

    // prologue: stage K-tile 0 into buffer 0 (4 loads/thread)
    async16(ap, &As[0][sr * 32]);
    async16(ap + 16 * DM, &As[0][(sr + 16) * 32]);
    async16(bp, &Bs[0][sr * 32]);
    async16(bp + 16 * DM, &Bs[0][(sr + 16) * 32]);

    #pragma unroll 2
    for (int kt = 0; kt < DM / 32; ++kt) {
        int cur = kt & 1;
        if (kt + 1 < DM / 32) {
            int k0 = (kt + 1) * 32;
            // prefetch next tile into the other buffer (free since last barrier)
            async16(ap + k0, &As[cur ^ 1][sr * 32]);
            async16(ap + k0 + 16 * DM, &As[cur ^ 1][(sr + 16) * 32]);
            async16(bp + k0, &Bs[cur ^ 1][sr * 32]);
            async16(bp + k0 + 16 * DM, &Bs[cur ^ 1][(sr + 16) * 32]);
            // wait only for the CURRENT tile's 4 loads (leave 4 in flight)
            asm volatile("s_waitcnt vmcnt(4)" ::: "memory");
        } else {
            asm volatile("s_waitcnt vmcnt(0)" ::: "memory");
        }
        __builtin_amdgcn_s_barrier();   // current tile visible to all waves

        f16x8 af[4], bfr[4];
        #pragma unroll
        for (int i = 0; i < 4; ++i)
            af[i] = *(const f16x8*)&As[cur][(wm * 64 + i * 16 + fm) * 32 + fs];
        #pragma unroll
        for (int j = 0; j < 4; ++j)
            bfr[j] = *(const f16x8*)&Bs[cur][(wn * 64 + j * 16 + fm) * 32 + fs];
        #pragma unroll
        for (int ci = 0; ci < 4; ++ci)
            #pragma unroll
            for (int ri = 0; ri < 4; ++ri)
                acc[ci][ri] = __builtin_amdgcn_mfma_f32_16x16x32_f16(bfr[ci], af[ri], acc[ci][ri], 0, 0, 0);
        __builtin_amdgcn_s_barrier();   // all waves done reading buf[cur]
        asm volatile("" ::: "memory");
    }

    int row0 = (int)rowBase + wm * 64;
    int col0 = cb * 128 + wn * 64;
    // bias: 4 consecutive cols per (ci), 16B-aligned
    float4 bv[4];
    #pragma unroll
    for (int ci = 0; ci < 4; ++ci)
        bv[ci] = *(const float4*)&bias[col0 + ci * 16 + (lane >> 4) * 4];
    #pragma unroll
    for (int ri = 0; ri < 4; ++ri) {
        int row = row0 + ri * 16 + (lane & 15);
        if (row < M) {
            #pragma unroll
            for (int ci = 0; ci < 4; ++ci) {
                int c0 = col0 + ci * 16 + (lane >> 4) * 4;
                f16x4 o;
                #pragma unroll
                for (int r = 0; r < 4; ++r) {
                    float v = acc[ci][ri][r] + (&bv[ci].x)[r];
                    if (ACT == ACT_RELU) v = v > 0.f ? v : 0.f;
                    if (ACT == ACT_GELU) v = gelu_f(v);
                    o[r] = (f16)v;
                }
                *(f16x4*)&C[(long)row * DM + c0] = o;
            }
        }
    }
}

extern "C" void kernel_launch(void* const* d_in, const int* in_sizes, int n_in,
                              void* d_out, int out_size, void* d_ws, size_t ws_size,
                              hipStream_t stream) {
    const int* x  = (const int*)d_in[0];
    const int* ea = (const int*)d_in[1];
    const int* ei = (const int*)d_in[2];
    const float* atom_emb  = (const float*)d_in[3];
    const float* atom_ln_g = (const float*)d_in[4];
    const float* atom_ln_b = (const float*)d_in[5];
    const float* atom_w1   = (const float*)d_in[6];
    const float* atom_b1   = (const float*)d_in[7];
    const float* atom_w2   = (const float*)d_in[8];
    const float* atom_b2   = (const float*)d_in[9];
    const float* bond_emb  = (const float*)d_in[10];
    const float* bond_ln_g = (const float*)d_in[11];
    const float* bond_ln_b = (const float*)d_in[12];
    const float* bond_w1   = (const float*)d_in[13];
    const float* bond_b1   = (const float*)d_in[14];
    const float* bond_w2   = (const float*)d_in[15];
    const float* bond_b2   = (const float*)d_in[16];
    const float* conv_w1   = (const float*)d_in[17];
    const float* conv_b1   = (const float*)d_in[18];
    const float* conv_w2   = (const float*)d_in[19];
    const float* conv_b2   = (const float*)d_in[20];
    const float* ln_g      = (const float*)d_in[21];
    const float* ln_b      = (const float*)d_in[22];

    const int N = in_sizes[0] / 9;
    const int E = in_sizes[1] / 3;
    const int V = in_sizes[10] / (3 * DM);  // bond vocab (8) -> V^3 combos (512)
    const int nC = V * V * V;
    const long SZ = (long)DM * DM;

    // ---- workspace: WT | Q | h | T | key | ids3 (~170 MiB) ----
    char* ws = (char*)d_ws;
    size_t off = 0;
    f16* WT  = (f16*)(ws + off); off += ((size_t)12 * SZ * 2 + 4095) & ~(size_t)4095;
    f16* Q   = (f16*)(ws + off); off += ((size_t)CHUNK * DM * 2 + 4095) & ~(size_t)4095;
    f16* h   = (f16*)(ws + off); off += ((size_t)N * DM * 2 + 4095) & ~(size_t)4095;
    f16* T   = (f16*)(ws + off); off += ((size_t)((nC + 127) & ~127) * DM * 2 + 4095) & ~(size_t)4095;
    int* key = (int*)(ws + off); off += ((size_t)E * 4 + 4095) & ~(size_t)4095;
    int* ids3 = (int*)(ws + off); off += ((size_t)nC * 12 + 4095) & ~(size_t)4095;
    // d_out region (N*DM fp32 = 153.6MB): low half = f16 U scratch (<=76.9MB);
    // head/next parked at +120MB, only clobbered by the final fp32 LN write.
    f16*   U    = (f16*)d_out;
    int*   head = (int*)((char*)d_out + 120000000);
    int*   nxt  = head + N;

    dim3 tb(32, 8), tg(24, 24);
    transpose768<<<tg, tb, 0, stream>>>(atom_w1, WT + 0 * SZ);
    transpose768<<<tg, tb, 0, stream>>>(atom_w2, WT + 1 * SZ);
    transpose768<<<tg, tb, 0, stream>>>(bond_w1, WT + 2 * SZ);
    transpose768<<<tg, tb, 0, stream>>>(bond_w2, WT + 3 * SZ);
    for (int l = 0; l < NLAYERS; ++l) {
        transpose768<<<tg, tb, 0, stream>>>(conv_w1 + l * SZ, WT + (4 + l) * SZ);
        transpose768<<<tg, tb, 0, stream>>>(conv_w2 + l * SZ, WT + (8 + l) * SZ);
    }

    // build dst->edges linked list + per-edge combo key (edge data is constant)
    hipMemsetAsync(head, 0xFF, (size_t)N * 4, stream);  // head = -1
    build_list_kernel<<<(E + 255) / 256, 256, 0, stream>>>(ei, E, head, nxt);
    make_key_kernel<<<(E + 255) / 256, 256, 0, stream>>>(ea, E, V, key);

    int rtN = (N + 127) / 128;
    dim3 gn(6 * rtN);   // 1-D, XCD-chunked swizzle inside the kernel

    // AtomEncoder: h = gelu(LN(sum emb) @ w1 + b1) @ w2 + b2   (Q -> U(d_out) -> h)
    embed_ln_kernel<<<N, 256, 0, stream>>>(x, 9, 128, atom_emb, atom_ln_g, atom_ln_b, Q);
    gemm768<ACT_GELU><<<gn, 256, 0, stream>>>(Q, WT + 0 * SZ, atom_b1, U, N);
    gemm768<ACT_NONE><<<gn, 256, 0, stream>>>(U, WT + 1 * SZ, atom_b2, h, N);

    // BondEncoder on the V^3 combo table only: Q -> U(d_out) -> T
    make_combo_ids<<<(nC + 255) / 256, 256, 0, stream>>>(V, nC, ids3);
    embed_ln_kernel<<<nC, 256, 0, stream>>>(ids3, 3, V, bond_emb, bond_ln_g, bond_ln_b, Q);
    dim3 gt(6 * ((nC + 127) / 128));
    gemm768<ACT_GELU><<<gt, 256, 0, stream>>>(Q, WT + 2 * SZ, bond_b1, U, nC);
    gemm768<ACT_NONE><<<gt, 256, 0, stream>>>(U, WT + 3 * SZ, bond_b2, T, nC);

    for (int l = 0; l < NLAYERS; ++l) {
        // z = h + sum_{j->i} relu(h[src] + T[key])  -> Q (f16), pure gather
        gather_agg_kernel<<<(N + 3) / 4, 256, 0, stream>>>(ei, head, nxt, key, h, T, Q, N);
        gemm768<ACT_RELU><<<gn, 256, 0, stream>>>(Q, WT + (4 + l) * SZ, conv_b1 + l * DM, U, N);  // U -> d_out
        gemm768<ACT_NONE><<<gn, 256, 0, stream>>>(U, WT + (8 + l) * SZ, conv_b2 + l * DM, Q, N);  // V -> Q
        if (l == NLAYERS - 1) {
            gelu_res_ln_kernel<float><<<N, 256, 0, stream>>>(Q, h, ln_g + l * DM, ln_b + l * DM, (float*)d_out);
        } else {
            gelu_res_ln_kernel<f16><<<N, 256, 0, stream>>>(Q, h, ln_g + l * DM, ln_b + l * DM, h);
        }
    }
}

// Round 7
// 1549.450 us; speedup vs baseline: 4.2187x; 1.0391x over previous
//
#include <hip/hip_runtime.h>

// GraphEncoder: GINE-style GNN, D=768, 4 layers. fp32 I/O, f16 intermediates +
// f16 MFMA GEMMs, fp32 accumulate/LN/scatter math.
//
// Round 9:
//  - Revert r8's 2-phase dbuf (compiler re-inserts vmcnt(0) before dependent
//    ds_reads -> pipeline defeated, 110->118us regression; matches guide
//    m131/m139).
//  - BK 32 -> 64, single-buffered (32KB LDS): halves the per-K-loop count of
//    stage->drain->barrier exposures (24 -> 12), 32 MFMA + 16 ds_read per
//    barrier pair. Swizzle updated for 128B rows: 16B-slot s ^= row&7 on BOTH
//    staging source col and ds_read col (rule #21); 2-way residual = free.
//  - Keep r8's __expf-based gelu (VALUBusy 46->30 confirmed).
//
// Kept: operand-swapped MFMA epilogue (8B f16x4 C stores, WRITE=ideal 77MB),
// XCD-chunked 1-D grid swizzle (FETCH 238->54MB), deduped bond encoder
// (512-combo table), linked-list gather aggregation (no float atomics).
//
// Workspace: [WT 12x768x768 f16 | Q 50048x768 f16 | h Nx768 f16 | T | key | ids3]
// d_out (Nx768 fp32, 153.6MB): low half = f16 U scratch; head/next parked at
// +120MB (clobbered only by the final fp32 LN write, which covers all of d_out).

#define DM 768
#define NLAYERS 4
#define CHUNK 50048  // row capacity for Q (multiple of 128, >= N)

typedef _Float16 f16;
typedef __attribute__((ext_vector_type(8))) _Float16 f16x8;
typedef __attribute__((ext_vector_type(4))) _Float16 f16x4;
typedef __attribute__((ext_vector_type(4))) float f32x4;

// gelu(x) = 0.5x(1+tanh(0.79788456(x+0.044715x^3))), tanh via exp:
// tanh(u) = sign(u) * (1 - a)/(1 + a), a = exp(-2|u|)  (a->0 saturates cleanly)
__device__ __forceinline__ float gelu_f(float x) {
    float u = 0.7978845608028654f * (x + 0.044715f * x * x * x);
    float a = __expf(-2.0f * fabsf(u));
    float t = (1.0f - a) / (1.0f + a);
    t = copysignf(t, u);
    return 0.5f * x * (1.0f + t);
}
__device__ __forceinline__ void async16(const void* g, void* l) {
    __builtin_amdgcn_global_load_lds((const __attribute__((address_space(1))) void*)g,
                                     (__attribute__((address_space(3))) void*)l,
                                     16, 0, 0);
}

// bijective XCD-chunked swizzle (m204): XCD k = b%8 gets a contiguous range of
// work ids; within the range, original b/8 order is preserved.
__device__ __forceinline__ int xcd_swizzle(int b, int nb) {
    int xcd = b & 7;
    int pos = b >> 3;
    int q = nb >> 3, r = nb & 7;
    int base = (xcd < r) ? xcd * (q + 1) : r * (q + 1) + (xcd - r) * q;
    return base + pos;
}

__device__ __forceinline__ void block_reduce2(float& s1, float& s2, float* sm) {
    #pragma unroll
    for (int off = 32; off > 0; off >>= 1) {
        s1 += __shfl_down(s1, off);
        s2 += __shfl_down(s2, off);
    }
    int lane = threadIdx.x & 63, wid = threadIdx.x >> 6;
    if (lane == 0) { sm[wid * 2] = s1; sm[wid * 2 + 1] = s2; }
    __syncthreads();
    s1 = sm[0] + sm[2] + sm[4] + sm[6];
    s2 = sm[1] + sm[3] + sm[5] + sm[7];
}

// -------- weight transpose + fp32->fp16: Wt[n][k] = W[k][n], 768x768 ----------
__global__ __launch_bounds__(256) void transpose768(
    const float* __restrict__ W, f16* __restrict__ Wt) {
    __shared__ float t[32][33];
    int tx = threadIdx.x, ty = threadIdx.y;
    int c0 = blockIdx.x * 32, r0 = blockIdx.y * 32;
    #pragma unroll
    for (int j = 0; j < 32; j += 8) t[ty + j][tx] = W[(r0 + ty + j) * DM + c0 + tx];
    __syncthreads();
    #pragma unroll
    for (int j = 0; j < 32; j += 8) Wt[(long)(c0 + ty + j) * DM + r0 + tx] = (f16)t[tx][ty + j];
}

// -------- embedding-sum + LayerNorm (encoder front), fp32 in, fp16 out ----------
__global__ __launch_bounds__(256) void embed_ln_kernel(
    const int* __restrict__ ids, int F, int V,
    const float* __restrict__ emb,
    const float* __restrict__ g, const float* __restrict__ b,
    f16* __restrict__ out) {
    int m = blockIdx.x, tid = threadIdx.x;
    float v[3] = {0.f, 0.f, 0.f};
    for (int f = 0; f < F; ++f) {
        int id = ids[(long)m * F + f];
        const float* row = emb + ((long)f * V + id) * DM;
        v[0] += row[tid];
        v[1] += row[tid + 256];
        v[2] += row[tid + 512];
    }
    float s1 = v[0] + v[1] + v[2];
    float s2 = v[0] * v[0] + v[1] * v[1] + v[2] * v[2];
    __shared__ float sm[8];
    block_reduce2(s1, s2, sm);
    float mean = s1 * (1.f / DM);
    float var = s2 * (1.f / DM) - mean * mean;
    float rstd = rsqrtf(var + 1e-5f);
    #pragma unroll
    for (int q = 0; q < 3; ++q) {
        int d = tid + q * 256;
        out[(long)m * DM + d] = (f16)((v[q] - mean) * rstd * g[d] + b[d]);
    }
}

// -------- gelu(U) + h_in -> LayerNorm -> out ----------
template <typename OUT>
__global__ __launch_bounds__(256) void gelu_res_ln_kernel(
    const f16* __restrict__ U, const f16* __restrict__ hin,
    const float* __restrict__ g, const float* __restrict__ b,
    OUT* __restrict__ out) {
    int m = blockIdx.x, tid = threadIdx.x;
    float v[3];
    #pragma unroll
    for (int q = 0; q < 3; ++q) {
        int d = tid + q * 256;
        v[q] = gelu_f((float)U[(long)m * DM + d]) + (float)hin[(long)m * DM + d];
    }
    float s1 = v[0] + v[1] + v[2];
    float s2 = v[0] * v[0] + v[1] * v[1] + v[2] * v[2];
    __shared__ float sm[8];
    block_reduce2(s1, s2, sm);
    float mean = s1 * (1.f / DM);
    float var = s2 * (1.f / DM) - mean * mean;
    float rstd = rsqrtf(var + 1e-5f);
    #pragma unroll
    for (int q = 0; q < 3; ++q) {
        int d = tid + q * 256;
        out[(long)m * DM + d] = (OUT)((v[q] - mean) * rstd * g[d] + b[d]);
    }
}

// -------- bond-combo helpers: ids for all V^3 combos; per-edge key ----------
__global__ __launch_bounds__(256) void make_combo_ids(
    int V, int nC, int* __restrict__ ids) {
    int c = blockIdx.x * 256 + threadIdx.x;
    if (c >= nC) return;
    ids[c * 3 + 0] = c / (V * V);
    ids[c * 3 + 1] = (c / V) % V;
    ids[c * 3 + 2] = c % V;
}
__global__ __launch_bounds__(256) void make_key_kernel(
    const int* __restrict__ ea, int E, int V, int* __restrict__ key) {
    int e = blockIdx.x * 256 + threadIdx.x;
    if (e >= E) return;
    key[e] = (ea[e * 3 + 0] * V + ea[e * 3 + 1]) * V + ea[e * 3 + 2];
}

// -------- build per-dst edge linked list (once; edge_index is layer-invariant) --
__global__ __launch_bounds__(256) void build_list_kernel(
    const int* __restrict__ ei, int E,
    int* __restrict__ head, int* __restrict__ nxt) {
    int e = blockIdx.x * 256 + threadIdx.x;
    if (e >= E) return;
    int dst = ei[E + e];
    nxt[e] = atomicExch(&head[dst], e);  // device-scope; order irrelevant (sum)
}

// -------- per-node gather aggregation: z[n] = h[n] + sum relu(h[src]+T[key]) --
// One wave per node; wave-uniform list walk (no divergence). 12 f16/lane.
// fp32 in-register accumulate. Edge features come from the 512-row combo
// table T (L2-resident) via key[edge].
__global__ __launch_bounds__(256) void gather_agg_kernel(
    const int* __restrict__ ei,
    const int* __restrict__ head, const int* __restrict__ nxt,
    const int* __restrict__ key,
    const f16* __restrict__ h, const f16* __restrict__ T,
    f16* __restrict__ z, int N) {
    int node = blockIdx.x * 4 + (threadIdx.x >> 6);
    if (node >= N) return;
    int lane = threadIdx.x & 63;
    int base = lane * 12;

    const f16* hr = h + (long)node * DM + base;
    f16x4 v0 = *(const f16x4*)&hr[0];
    f16x4 v1 = *(const f16x4*)&hr[4];
    f16x4 v2 = *(const f16x4*)&hr[8];
    float acc[12];
    #pragma unroll
    for (int j = 0; j < 4; ++j) {
        acc[j]     = (float)v0[j];
        acc[4 + j] = (float)v1[j];
        acc[8 + j] = (float)v2[j];
    }

    int ecur = head[node];
    while (ecur >= 0) {
        int enext = nxt[ecur];          // issue chase early; rows overlap it
        int src = ei[ecur];
        int kq = key[ecur];
        const f16* sr = h + (long)src * DM + base;
        const f16* er = T + (long)kq * DM + base;
        f16x4 a0 = *(const f16x4*)&sr[0];
        f16x4 a1 = *(const f16x4*)&sr[4];
        f16x4 a2 = *(const f16x4*)&sr[8];
        f16x4 b0 = *(const f16x4*)&er[0];
        f16x4 b1 = *(const f16x4*)&er[4];
        f16x4 b2 = *(const f16x4*)&er[8];
        #pragma unroll
        for (int j = 0; j < 4; ++j) {
            float m0 = (float)a0[j] + (float)b0[j];
            float m1 = (float)a1[j] + (float)b1[j];
            float m2 = (float)a2[j] + (float)b2[j];
            if (m0 > 0.f) acc[j]     += m0;
            if (m1 > 0.f) acc[4 + j] += m1;
            if (m2 > 0.f) acc[8 + j] += m2;
        }
        ecur = enext;
    }

    f16* zr = z + (long)node * DM + base;
    f16x4 o0, o1, o2;
    #pragma unroll
    for (int j = 0; j < 4; ++j) {
        o0[j] = (f16)acc[j];
        o1[j] = (f16)acc[4 + j];
        o2[j] = (f16)acc[8 + j];
    }
    *(f16x4*)&zr[0] = o0;
    *(f16x4*)&zr[4] = o1;
    *(f16x4*)&zr[8] = o2;
}

// -------- GEMM: C[M,768] = act(A[M,768] @ W + bias), Bt[n][k] = W[k][n] ----------
// 1-D grid, XCD-chunked swizzle. MFMA operands swapped (transposed D) for 8B
// f16x4 C stores. BK=64 single-buffered (32KB LDS): 12 K-iterations, 32 MFMA +
// 16 ds_read_b128 per barrier pair.
// LDS tile [128][64] f16 (128B rows): 16B-slot swizzle s ^= row&7 on BOTH the
// staging source column and the ds_read column (rule #21). Staged rows within
// one async16 differ only in row = srow (mod 8), so source col is per-lane
// constant; reads hit 8 distinct slots per 8 lanes -> 2-way residual (free).
#define ACT_NONE 0
#define ACT_RELU 1
#define ACT_GELU 2

template <int ACT>
__global__ __launch_bounds__(256, 2) void gemm768(
    const f16* __restrict__ A,      // [M,768] f16; rows may overread <=127 past M (mapped)
    const f16* __restrict__ Bt,     // [768,768] f16, Bt[n][k] = W[k][n]
    const float* __restrict__ bias, // [768] fp32
    f16* __restrict__ C,            // [M,768] f16
    int M) {
    __shared__ f16 As[128 * 64];
    __shared__ f16 Bs[128 * 64];
    int tid = threadIdx.x;
    int lane = tid & 63;
    int wid = tid >> 6;
    int wm = wid >> 1, wn = wid & 1;

    int wg = xcd_swizzle(blockIdx.x, gridDim.x);
    int rt = wg / 6, cb = wg - rt * 6;
    long rowBase = (long)rt * 128;
    const f16* Ab = A + rowBase * DM;
    const f16* Bb = Bt + (long)cb * 128 * DM;

    f32x4 acc[4][4];  // acc[ci][ri]: ci = col subtile (from Bt), ri = row subtile
    #pragma unroll
    for (int i = 0; i < 4; ++i)
        #pragma unroll
        for (int j = 0; j < 4; ++j) acc[i][j] = (f32x4){0.f, 0.f, 0.f, 0.f};

    // ---- staging geometry (BK=64): wave stages rows [wid*32, wid*32+32) of
    // A and B; each async16 covers 8 rows x 8 slots. lane -> row srow, slot.
    int sr = wid * 32;
    int srow = lane >> 3;              // 0..7 within the 8-row group
    int sslot = lane & 7;              // 16B slot 0..7
    int scol = ((sslot ^ srow) * 8);   // swizzled source column (elems)
    const f16* gA = Ab + (long)(sr + srow) * DM + scol;
    const f16* gB = Bb + (long)(sr + srow) * DM + scol;

    // ---- read geometry: frag row r = base + fm, slot = kslot ^ (fm&7)
    int fm = lane & 15;
    int fq = lane >> 4;                // 0..3
    int rs0 = ((fq ^ (fm & 7)) * 8);         // kk=0 half: kslot = fq
    int rs1 = (((4 + fq) ^ (fm & 7)) * 8);   // kk=32 half: kslot = 4+fq

    for (int kt = 0; kt < DM / 64; ++kt) {
        int k0 = kt * 64;
        #pragma unroll
        for (int j = 0; j < 4; ++j) {
            async16(gA + k0 + j * 8 * DM, &As[(sr + j * 8) * 64]);
            async16(gB + k0 + j * 8 * DM, &Bs[(sr + j * 8) * 64]);
        }
        __syncthreads();

        f16x8 af0[4], bf0[4], af1[4], bf1[4];
        #pragma unroll
        for (int i = 0; i < 4; ++i) {
            int ra = (wm * 64 + i * 16 + fm) * 64;
            af0[i] = *(const f16x8*)&As[ra + rs0];
            af1[i] = *(const f16x8*)&As[ra + rs1];
        }
        #pragma unroll
        for (int j = 0; j < 4; ++j) {
            int rb = (wn * 64 + j * 16 + fm) * 64;
            bf0[j] = *(const f16x8*)&Bs[rb + rs0];
            bf1[j] = *(const f16x8*)&Bs[rb + rs1];
        }
        #pragma unroll
        for (int ci = 0; ci < 4; ++ci)
            #pragma unroll
            for (int ri = 0; ri < 4; ++ri)
                acc[ci][ri] = __builtin_amdgcn_mfma_f32_16x16x32_f16(bf0[ci], af0[ri], acc[ci][ri], 0, 0, 0);
        #pragma unroll
        for (int ci = 0; ci < 4; ++ci)
            #pragma unroll
            for (int ri = 0; ri < 4; ++ri)
                acc[ci][ri] = __builtin_amdgcn_mfma_f32_16x16x32_f16(bf1[ci], af1[ri], acc[ci][ri], 0, 0, 0);
        __syncthreads();
    }

    int row0 = (int)rowBase + wm * 64;
    int col0 = cb * 128 + wn * 64;
    // bias: 4 consecutive cols per (ci), 16B-aligned
    float4 bv[4];
    #pragma unroll
    for (int ci = 0; ci < 4; ++ci)
        bv[ci] = *(const float4*)&bias[col0 + ci * 16 + (lane >> 4) * 4];
    #pragma unroll
    for (int ri = 0; ri < 4; ++ri) {
        int row = row0 + ri * 16 + (lane & 15);
        if (row < M) {
            #pragma unroll
            for (int ci = 0; ci < 4; ++ci) {
                int c0 = col0 + ci * 16 + (lane >> 4) * 4;
                f16x4 o;
                #pragma unroll
                for (int r = 0; r < 4; ++r) {
                    float v = acc[ci][ri][r] + (&bv[ci].x)[r];
                    if (ACT == ACT_RELU) v = v > 0.f ? v : 0.f;
                    if (ACT == ACT_GELU) v = gelu_f(v);
                    o[r] = (f16)v;
                }
                *(f16x4*)&C[(long)row * DM + c0] = o;
            }
        }
    }
}

extern "C" void kernel_launch(void* const* d_in, const int* in_sizes, int n_in,
                              void* d_out, int out_size, void* d_ws, size_t ws_size,
                              hipStream_t stream) {
    const int* x  = (const int*)d_in[0];
    const int* ea = (const int*)d_in[1];
    const int* ei = (const int*)d_in[2];
    const float* atom_emb  = (const float*)d_in[3];
    const float* atom_ln_g = (const float*)d_in[4];
    const float* atom_ln_b = (const float*)d_in[5];
    const float* atom_w1   = (const float*)d_in[6];
    const float* atom_b1   = (const float*)d_in[7];
    const float* atom_w2   = (const float*)d_in[8];
    const float* atom_b2   = (const float*)d_in[9];
    const float* bond_emb  = (const float*)d_in[10];
    const float* bond_ln_g = (const float*)d_in[11];
    const float* bond_ln_b = (const float*)d_in[12];
    const float* bond_w1   = (const float*)d_in[13];
    const float* bond_b1   = (const float*)d_in[14];
    const float* bond_w2   = (const float*)d_in[15];
    const float* bond_b2   = (const float*)d_in[16];
    const float* conv_w1   = (const float*)d_in[17];
    const float* conv_b1   = (const float*)d_in[18];
    const float* conv_w2   = (const float*)d_in[19];
    const float* conv_b2   = (const float*)d_in[20];
    const float* ln_g      = (const float*)d_in[21];
    const float* ln_b      = (const float*)d_in[22];

    const int N = in_sizes[0] / 9;
    const int E = in_sizes[1] / 3;
    const int V = in_sizes[10] / (3 * DM);  // bond vocab (8) -> V^3 combos (512)
    const int nC = V * V * V;
    const long SZ = (long)DM * DM;

    // ---- workspace: WT | Q | h | T | key | ids3 (~170 MiB) ----
    char* ws = (char*)d_ws;
    size_t off = 0;
    f16* WT  = (f16*)(ws + off); off += ((size_t)12 * SZ * 2 + 4095) & ~(size_t)4095;
    f16* Q   = (f16*)(ws + off); off += ((size_t)CHUNK * DM * 2 + 4095) & ~(size_t)4095;
    f16* h   = (f16*)(ws + off); off += ((size_t)N * DM * 2 + 4095) & ~(size_t)4095;
    f16* T   = (f16*)(ws + off); off += ((size_t)((nC + 127) & ~127) * DM * 2 + 4095) & ~(size_t)4095;
    int* key = (int*)(ws + off); off += ((size_t)E * 4 + 4095) & ~(size_t)4095;
    int* ids3 = (int*)(ws + off); off += ((size_t)nC * 12 + 4095) & ~(size_t)4095;
    // d_out region (N*DM fp32 = 153.6MB): low half = f16 U scratch (<=76.9MB);
    // head/next parked at +120MB, only clobbered by the final fp32 LN write.
    f16*   U    = (f16*)d_out;
    int*   head = (int*)((char*)d_out + 120000000);
    int*   nxt  = head + N;

    dim3 tb(32, 8), tg(24, 24);
    transpose768<<<tg, tb, 0, stream>>>(atom_w1, WT + 0 * SZ);
    transpose768<<<tg, tb, 0, stream>>>(atom_w2, WT + 1 * SZ);
    transpose768<<<tg, tb, 0, stream>>>(bond_w1, WT + 2 * SZ);
    transpose768<<<tg, tb, 0, stream>>>(bond_w2, WT + 3 * SZ);
    for (int l = 0; l < NLAYERS; ++l) {
        transpose768<<<tg, tb, 0, stream>>>(conv_w1 + l * SZ, WT + (4 + l) * SZ);
        transpose768<<<tg, tb, 0, stream>>>(conv_w2 + l * SZ, WT + (8 + l) * SZ);
    }

    // build dst->edges linked list + per-edge combo key (edge data is constant)
    hipMemsetAsync(head, 0xFF, (size_t)N * 4, stream);  // head = -1
    build_list_kernel<<<(E + 255) / 256, 256, 0, stream>>>(ei, E, head, nxt);
    make_key_kernel<<<(E + 255) / 256, 256, 0, stream>>>(ea, E, V, key);

    int rtN = (N + 127) / 128;
    dim3 gn(6 * rtN);   // 1-D, XCD-chunked swizzle inside the kernel

    // AtomEncoder: h = gelu(LN(sum emb) @ w1 + b1) @ w2 + b2   (Q -> U(d_out) -> h)
    embed_ln_kernel<<<N, 256, 0, stream>>>(x, 9, 128, atom_emb, atom_ln_g, atom_ln_b, Q);
    gemm768<ACT_GELU><<<gn, 256, 0, stream>>>(Q, WT + 0 * SZ, atom_b1, U, N);
    gemm768<ACT_NONE><<<gn, 256, 0, stream>>>(U, WT + 1 * SZ, atom_b2, h, N);

    // BondEncoder on the V^3 combo table only: Q -> U(d_out) -> T
    make_combo_ids<<<(nC + 255) / 256, 256, 0, stream>>>(V, nC, ids3);
    embed_ln_kernel<<<nC, 256, 0, stream>>>(ids3, 3, V, bond_emb, bond_ln_g, bond_ln_b, Q);
    dim3 gt(6 * ((nC + 127) / 128));
    gemm768<ACT_GELU><<<gt, 256, 0, stream>>>(Q, WT + 2 * SZ, bond_b1, U, nC);
    gemm768<ACT_NONE><<<gt, 256, 0, stream>>>(U, WT + 3 * SZ, bond_b2, T, nC);

    for (int l = 0; l < NLAYERS; ++l) {
        // z = h + sum_{j->i} relu(h[src] + T[key])  -> Q (f16), pure gather
        gather_agg_kernel<<<(N + 3) / 4, 256, 0, stream>>>(ei, head, nxt, key, h, T, Q, N);
        gemm768<ACT_RELU><<<gn, 256, 0, stream>>>(Q, WT + (4 + l) * SZ, conv_b1 + l * DM, U, N);  // U -> d_out
        gemm768<ACT_NONE><<<gn, 256, 0, stream>>>(U, WT + (8 + l) * SZ, conv_b2 + l * DM, Q, N);  // V -> Q
        if (l == NLAYERS - 1) {
            gelu_res_ln_kernel<float><<<N, 256, 0, stream>>>(Q, h, ln_g + l * DM, ln_b + l * DM, (float*)d_out);
        } else {
            gelu_res_ln_kernel<f16><<<N, 256, 0, stream>>>(Q, h, ln_g + l * DM, ln_b + l * DM, h);
        }
    }
}

// Round 8
// 1377.005 us; speedup vs baseline: 4.7470x; 1.1252x over previous
//
#include <hip/hip_runtime.h>

// GraphEncoder: GINE-style GNN, D=768, 4 layers. fp32 I/O, f16 intermediates +
// f16 MFMA GEMMs, fp32 accumulate/LN/scatter math.
//
// Round 10: LN kernels -> wave-per-row. Round-9 counters: embed_ln_kernel is
// the #1 dispatch (97us, MfmaUtil 0, VALU 38%, HBM 15%) -- block-per-row with
// LDS reduce + 2 __syncthreads serializes ~7700cyc/block. New structure:
// 64 lanes x 12 elems = 768, 4 rows/block, shfl_xor butterfly reduce (no LDS,
// no barriers), float4/f16x4 vector loads+stores. Same for gelu_res_ln (x4).
//
// Kept: BK=64 single-buffer GEMM (r9: gemm768 left top-5, <96us), operand-
// swapped MFMA epilogue (WRITE=ideal), XCD-chunked grid swizzle (FETCH 54MB),
// LDS XOR-swizzle, __expf gelu, deduped bond encoder, linked-list gather.
//
// Workspace: [WT 12x768x768 f16 | Q 50048x768 f16 | h Nx768 f16 | T | key | ids3]
// d_out (Nx768 fp32, 153.6MB): low half = f16 U scratch; head/next parked at
// +120MB (clobbered only by the final fp32 LN write, which covers all of d_out).

#define DM 768
#define NLAYERS 4
#define CHUNK 50048  // row capacity for Q (multiple of 128, >= N)

typedef _Float16 f16;
typedef __attribute__((ext_vector_type(8))) _Float16 f16x8;
typedef __attribute__((ext_vector_type(4))) _Float16 f16x4;
typedef __attribute__((ext_vector_type(4))) float f32x4;

// gelu(x) = 0.5x(1+tanh(0.79788456(x+0.044715x^3))), tanh via exp:
// tanh(u) = sign(u) * (1 - a)/(1 + a), a = exp(-2|u|)  (a->0 saturates cleanly)
__device__ __forceinline__ float gelu_f(float x) {
    float u = 0.7978845608028654f * (x + 0.044715f * x * x * x);
    float a = __expf(-2.0f * fabsf(u));
    float t = (1.0f - a) / (1.0f + a);
    t = copysignf(t, u);
    return 0.5f * x * (1.0f + t);
}
__device__ __forceinline__ void async16(const void* g, void* l) {
    __builtin_amdgcn_global_load_lds((const __attribute__((address_space(1))) void*)g,
                                     (__attribute__((address_space(3))) void*)l,
                                     16, 0, 0);
}

// bijective XCD-chunked swizzle (m204): XCD k = b%8 gets a contiguous range of
// work ids; within the range, original b/8 order is preserved.
__device__ __forceinline__ int xcd_swizzle(int b, int nb) {
    int xcd = b & 7;
    int pos = b >> 3;
    int q = nb >> 3, r = nb & 7;
    int base = (xcd < r) ? xcd * (q + 1) : r * (q + 1) + (xcd - r) * q;
    return base + pos;
}

// -------- weight transpose + fp32->fp16: Wt[n][k] = W[k][n], 768x768 ----------
__global__ __launch_bounds__(256) void transpose768(
    const float* __restrict__ W, f16* __restrict__ Wt) {
    __shared__ float t[32][33];
    int tx = threadIdx.x, ty = threadIdx.y;
    int c0 = blockIdx.x * 32, r0 = blockIdx.y * 32;
    #pragma unroll
    for (int j = 0; j < 32; j += 8) t[ty + j][tx] = W[(r0 + ty + j) * DM + c0 + tx];
    __syncthreads();
    #pragma unroll
    for (int j = 0; j < 32; j += 8) Wt[(long)(c0 + ty + j) * DM + r0 + tx] = (f16)t[tx][ty + j];
}

// -------- embedding-sum + LayerNorm, wave-per-row (no LDS, no barriers) ------
// 64 lanes x 12 elems = 768; 4 rows/block; shfl_xor butterfly reduce.
__global__ __launch_bounds__(256) void embed_ln_wave(
    const int* __restrict__ ids, int F, int V,
    const float* __restrict__ emb,
    const float* __restrict__ g, const float* __restrict__ b,
    f16* __restrict__ out, int M) {
    int row = blockIdx.x * 4 + (threadIdx.x >> 6);
    if (row >= M) return;
    int lane = threadIdx.x & 63;
    int base = lane * 12;

    float v[12];
    #pragma unroll
    for (int j = 0; j < 12; ++j) v[j] = 0.f;
    for (int f = 0; f < F; ++f) {
        int id = ids[(long)row * F + f];
        const float* r = emb + ((long)f * V + id) * DM + base;
        float4 r0 = *(const float4*)&r[0];
        float4 r1 = *(const float4*)&r[4];
        float4 r2 = *(const float4*)&r[8];
        v[0] += r0.x; v[1] += r0.y; v[2]  += r0.z; v[3]  += r0.w;
        v[4] += r1.x; v[5] += r1.y; v[6]  += r1.z; v[7]  += r1.w;
        v[8] += r2.x; v[9] += r2.y; v[10] += r2.z; v[11] += r2.w;
    }
    float s1 = 0.f, s2 = 0.f;
    #pragma unroll
    for (int j = 0; j < 12; ++j) { s1 += v[j]; s2 += v[j] * v[j]; }
    #pragma unroll
    for (int off = 32; off > 0; off >>= 1) {
        s1 += __shfl_xor(s1, off);
        s2 += __shfl_xor(s2, off);
    }
    float mean = s1 * (1.f / DM);
    float var = s2 * (1.f / DM) - mean * mean;
    float rstd = rsqrtf(var + 1e-5f);

    float4 gv0 = *(const float4*)&g[base], gv1 = *(const float4*)&g[base + 4], gv2 = *(const float4*)&g[base + 8];
    float4 bv0 = *(const float4*)&b[base], bv1 = *(const float4*)&b[base + 4], bv2 = *(const float4*)&b[base + 8];
    float gg[12] = {gv0.x, gv0.y, gv0.z, gv0.w, gv1.x, gv1.y, gv1.z, gv1.w, gv2.x, gv2.y, gv2.z, gv2.w};
    float bb[12] = {bv0.x, bv0.y, bv0.z, bv0.w, bv1.x, bv1.y, bv1.z, bv1.w, bv2.x, bv2.y, bv2.z, bv2.w};
    f16* o = out + (long)row * DM + base;
    #pragma unroll
    for (int q = 0; q < 3; ++q) {
        f16x4 ov;
        #pragma unroll
        for (int r = 0; r < 4; ++r)
            ov[r] = (f16)((v[q * 4 + r] - mean) * rstd * gg[q * 4 + r] + bb[q * 4 + r]);
        *(f16x4*)&o[q * 4] = ov;
    }
}

// -------- gelu(U) + h_in -> LayerNorm -> out, wave-per-row ----------
template <typename OUT>
__global__ __launch_bounds__(256) void gelu_res_ln_wave(
    const f16* __restrict__ U, const f16* __restrict__ hin,
    const float* __restrict__ g, const float* __restrict__ b,
    OUT* __restrict__ out, int M) {
    int row = blockIdx.x * 4 + (threadIdx.x >> 6);
    if (row >= M) return;
    int lane = threadIdx.x & 63;
    int base = lane * 12;

    const f16* up = U + (long)row * DM + base;
    const f16* hp = hin + (long)row * DM + base;
    float v[12];
    #pragma unroll
    for (int q = 0; q < 3; ++q) {
        f16x4 uv = *(const f16x4*)&up[q * 4];
        f16x4 hv = *(const f16x4*)&hp[q * 4];
        #pragma unroll
        for (int r = 0; r < 4; ++r)
            v[q * 4 + r] = gelu_f((float)uv[r]) + (float)hv[r];
    }
    float s1 = 0.f, s2 = 0.f;
    #pragma unroll
    for (int j = 0; j < 12; ++j) { s1 += v[j]; s2 += v[j] * v[j]; }
    #pragma unroll
    for (int off = 32; off > 0; off >>= 1) {
        s1 += __shfl_xor(s1, off);
        s2 += __shfl_xor(s2, off);
    }
    float mean = s1 * (1.f / DM);
    float var = s2 * (1.f / DM) - mean * mean;
    float rstd = rsqrtf(var + 1e-5f);

    float4 gv0 = *(const float4*)&g[base], gv1 = *(const float4*)&g[base + 4], gv2 = *(const float4*)&g[base + 8];
    float4 bv0 = *(const float4*)&b[base], bv1 = *(const float4*)&b[base + 4], bv2 = *(const float4*)&b[base + 8];
    float gg[12] = {gv0.x, gv0.y, gv0.z, gv0.w, gv1.x, gv1.y, gv1.z, gv1.w, gv2.x, gv2.y, gv2.z, gv2.w};
    float bb[12] = {bv0.x, bv0.y, bv0.z, bv0.w, bv1.x, bv1.y, bv1.z, bv1.w, bv2.x, bv2.y, bv2.z, bv2.w};
    #pragma unroll
    for (int q = 0; q < 3; ++q) {
        float w0 = (v[q * 4 + 0] - mean) * rstd * gg[q * 4 + 0] + bb[q * 4 + 0];
        float w1 = (v[q * 4 + 1] - mean) * rstd * gg[q * 4 + 1] + bb[q * 4 + 1];
        float w2 = (v[q * 4 + 2] - mean) * rstd * gg[q * 4 + 2] + bb[q * 4 + 2];
        float w3 = (v[q * 4 + 3] - mean) * rstd * gg[q * 4 + 3] + bb[q * 4 + 3];
        if constexpr (sizeof(OUT) == 2) {
            f16x4 ov; ov[0] = (f16)w0; ov[1] = (f16)w1; ov[2] = (f16)w2; ov[3] = (f16)w3;
            *(f16x4*)&out[(long)row * DM + base + q * 4] = ov;
        } else {
            float4 ov; ov.x = w0; ov.y = w1; ov.z = w2; ov.w = w3;
            *(float4*)&out[(long)row * DM + base + q * 4] = ov;
        }
    }
}

// -------- bond-combo helpers: ids for all V^3 combos; per-edge key ----------
__global__ __launch_bounds__(256) void make_combo_ids(
    int V, int nC, int* __restrict__ ids) {
    int c = blockIdx.x * 256 + threadIdx.x;
    if (c >= nC) return;
    ids[c * 3 + 0] = c / (V * V);
    ids[c * 3 + 1] = (c / V) % V;
    ids[c * 3 + 2] = c % V;
}
__global__ __launch_bounds__(256) void make_key_kernel(
    const int* __restrict__ ea, int E, int V, int* __restrict__ key) {
    int e = blockIdx.x * 256 + threadIdx.x;
    if (e >= E) return;
    key[e] = (ea[e * 3 + 0] * V + ea[e * 3 + 1]) * V + ea[e * 3 + 2];
}

// -------- build per-dst edge linked list (once; edge_index is layer-invariant) --
__global__ __launch_bounds__(256) void build_list_kernel(
    const int* __restrict__ ei, int E,
    int* __restrict__ head, int* __restrict__ nxt) {
    int e = blockIdx.x * 256 + threadIdx.x;
    if (e >= E) return;
    int dst = ei[E + e];
    nxt[e] = atomicExch(&head[dst], e);  // device-scope; order irrelevant (sum)
}

// -------- per-node gather aggregation: z[n] = h[n] + sum relu(h[src]+T[key]) --
// One wave per node; wave-uniform list walk (no divergence). 12 f16/lane.
// fp32 in-register accumulate. Edge features come from the 512-row combo
// table T (L2-resident) via key[edge].
__global__ __launch_bounds__(256) void gather_agg_kernel(
    const int* __restrict__ ei,
    const int* __restrict__ head, const int* __restrict__ nxt,
    const int* __restrict__ key,
    const f16* __restrict__ h, const f16* __restrict__ T,
    f16* __restrict__ z, int N) {
    int node = blockIdx.x * 4 + (threadIdx.x >> 6);
    if (node >= N) return;
    int lane = threadIdx.x & 63;
    int base = lane * 12;

    const f16* hr = h + (long)node * DM + base;
    f16x4 v0 = *(const f16x4*)&hr[0];
    f16x4 v1 = *(const f16x4*)&hr[4];
    f16x4 v2 = *(const f16x4*)&hr[8];
    float acc[12];
    #pragma unroll
    for (int j = 0; j < 4; ++j) {
        acc[j]     = (float)v0[j];
        acc[4 + j] = (float)v1[j];
        acc[8 + j] = (float)v2[j];
    }

    int ecur = head[node];
    while (ecur >= 0) {
        int enext = nxt[ecur];          // issue chase early; rows overlap it
        int src = ei[ecur];
        int kq = key[ecur];
        const f16* sr = h + (long)src * DM + base;
        const f16* er = T + (long)kq * DM + base;
        f16x4 a0 = *(const f16x4*)&sr[0];
        f16x4 a1 = *(const f16x4*)&sr[4];
        f16x4 a2 = *(const f16x4*)&sr[8];
        f16x4 b0 = *(const f16x4*)&er[0];
        f16x4 b1 = *(const f16x4*)&er[4];
        f16x4 b2 = *(const f16x4*)&er[8];
        #pragma unroll
        for (int j = 0; j < 4; ++j) {
            float m0 = (float)a0[j] + (float)b0[j];
            float m1 = (float)a1[j] + (float)b1[j];
            float m2 = (float)a2[j] + (float)b2[j];
            if (m0 > 0.f) acc[j]     += m0;
            if (m1 > 0.f) acc[4 + j] += m1;
            if (m2 > 0.f) acc[8 + j] += m2;
        }
        ecur = enext;
    }

    f16* zr = z + (long)node * DM + base;
    f16x4 o0, o1, o2;
    #pragma unroll
    for (int j = 0; j < 4; ++j) {
        o0[j] = (f16)acc[j];
        o1[j] = (f16)acc[4 + j];
        o2[j] = (f16)acc[8 + j];
    }
    *(f16x4*)&zr[0] = o0;
    *(f16x4*)&zr[4] = o1;
    *(f16x4*)&zr[8] = o2;
}

// -------- GEMM: C[M,768] = act(A[M,768] @ W + bias), Bt[n][k] = W[k][n] ----------
// 1-D grid, XCD-chunked swizzle. MFMA operands swapped (transposed D) for 8B
// f16x4 C stores. BK=64 single-buffered (32KB LDS): 12 K-iterations, 32 MFMA +
// 16 ds_read_b128 per barrier pair.
// LDS tile [128][64] f16 (128B rows): 16B-slot swizzle s ^= row&7 on BOTH the
// staging source column and the ds_read column (rule #21).
#define ACT_NONE 0
#define ACT_RELU 1
#define ACT_GELU 2

template <int ACT>
__global__ __launch_bounds__(256, 2) void gemm768(
    const f16* __restrict__ A,      // [M,768] f16; rows may overread <=127 past M (mapped)
    const f16* __restrict__ Bt,     // [768,768] f16, Bt[n][k] = W[k][n]
    const float* __restrict__ bias, // [768] fp32
    f16* __restrict__ C,            // [M,768] f16
    int M) {
    __shared__ f16 As[128 * 64];
    __shared__ f16 Bs[128 * 64];
    int tid = threadIdx.x;
    int lane = tid & 63;
    int wid = tid >> 6;
    int wm = wid >> 1, wn = wid & 1;

    int wg = xcd_swizzle(blockIdx.x, gridDim.x);
    int rt = wg / 6, cb = wg - rt * 6;
    long rowBase = (long)rt * 128;
    const f16* Ab = A + rowBase * DM;
    const f16* Bb = Bt + (long)cb * 128 * DM;

    f32x4 acc[4][4];  // acc[ci][ri]: ci = col subtile (from Bt), ri = row subtile
    #pragma unroll
    for (int i = 0; i < 4; ++i)
        #pragma unroll
        for (int j = 0; j < 4; ++j) acc[i][j] = (f32x4){0.f, 0.f, 0.f, 0.f};

    // ---- staging geometry (BK=64): wave stages rows [wid*32, wid*32+32) of
    // A and B; each async16 covers 8 rows x 8 slots. lane -> row srow, slot.
    int sr = wid * 32;
    int srow = lane >> 3;              // 0..7 within the 8-row group
    int sslot = lane & 7;              // 16B slot 0..7
    int scol = ((sslot ^ srow) * 8);   // swizzled source column (elems)
    const f16* gA = Ab + (long)(sr + srow) * DM + scol;
    const f16* gB = Bb + (long)(sr + srow) * DM + scol;

    // ---- read geometry: frag row r = base + fm, slot = kslot ^ (fm&7)
    int fm = lane & 15;
    int fq = lane >> 4;                // 0..3
    int rs0 = ((fq ^ (fm & 7)) * 8);         // kk=0 half: kslot = fq
    int rs1 = (((4 + fq) ^ (fm & 7)) * 8);   // kk=32 half: kslot = 4+fq

    for (int kt = 0; kt < DM / 64; ++kt) {
        int k0 = kt * 64;
        #pragma unroll
        for (int j = 0; j < 4; ++j) {
            async16(gA + k0 + j * 8 * DM, &As[(sr + j * 8) * 64]);
            async16(gB + k0 + j * 8 * DM, &Bs[(sr + j * 8) * 64]);
        }
        __syncthreads();

        f16x8 af0[4], bf0[4], af1[4], bf1[4];
        #pragma unroll
        for (int i = 0; i < 4; ++i) {
            int ra = (wm * 64 + i * 16 + fm) * 64;
            af0[i] = *(const f16x8*)&As[ra + rs0];
            af1[i] = *(const f16x8*)&As[ra + rs1];
        }
        #pragma unroll
        for (int j = 0; j < 4; ++j) {
            int rb = (wn * 64 + j * 16 + fm) * 64;
            bf0[j] = *(const f16x8*)&Bs[rb + rs0];
            bf1[j] = *(const f16x8*)&Bs[rb + rs1];
        }
        #pragma unroll
        for (int ci = 0; ci < 4; ++ci)
            #pragma unroll
            for (int ri = 0; ri < 4; ++ri)
                acc[ci][ri] = __builtin_amdgcn_mfma_f32_16x16x32_f16(bf0[ci], af0[ri], acc[ci][ri], 0, 0, 0);
        #pragma unroll
        for (int ci = 0; ci < 4; ++ci)
            #pragma unroll
            for (int ri = 0; ri < 4; ++ri)
                acc[ci][ri] = __builtin_amdgcn_mfma_f32_16x16x32_f16(bf1[ci], af1[ri], acc[ci][ri], 0, 0, 0);
        __syncthreads();
    }

    int row0 = (int)rowBase + wm * 64;
    int col0 = cb * 128 + wn * 64;
    // bias: 4 consecutive cols per (ci), 16B-aligned
    float4 bv[4];
    #pragma unroll
    for (int ci = 0; ci < 4; ++ci)
        bv[ci] = *(const float4*)&bias[col0 + ci * 16 + (lane >> 4) * 4];
    #pragma unroll
    for (int ri = 0; ri < 4; ++ri) {
        int row = row0 + ri * 16 + (lane & 15);
        if (row < M) {
            #pragma unroll
            for (int ci = 0; ci < 4; ++ci) {
                int c0 = col0 + ci * 16 + (lane >> 4) * 4;
                f16x4 o;
                #pragma unroll
                for (int r = 0; r < 4; ++r) {
                    float v = acc[ci][ri][r] + (&bv[ci].x)[r];
                    if (ACT == ACT_RELU) v = v > 0.f ? v : 0.f;
                    if (ACT == ACT_GELU) v = gelu_f(v);
                    o[r] = (f16)v;
                }
                *(f16x4*)&C[(long)row * DM + c0] = o;
            }
        }
    }
}

extern "C" void kernel_launch(void* const* d_in, const int* in_sizes, int n_in,
                              void* d_out, int out_size, void* d_ws, size_t ws_size,
                              hipStream_t stream) {
    const int* x  = (const int*)d_in[0];
    const int* ea = (const int*)d_in[1];
    const int* ei = (const int*)d_in[2];
    const float* atom_emb  = (const float*)d_in[3];
    const float* atom_ln_g = (const float*)d_in[4];
    const float* atom_ln_b = (const float*)d_in[5];
    const float* atom_w1   = (const float*)d_in[6];
    const float* atom_b1   = (const float*)d_in[7];
    const float* atom_w2   = (const float*)d_in[8];
    const float* atom_b2   = (const float*)d_in[9];
    const float* bond_emb  = (const float*)d_in[10];
    const float* bond_ln_g = (const float*)d_in[11];
    const float* bond_ln_b = (const float*)d_in[12];
    const float* bond_w1   = (const float*)d_in[13];
    const float* bond_b1   = (const float*)d_in[14];
    const float* bond_w2   = (const float*)d_in[15];
    const float* bond_b2   = (const float*)d_in[16];
    const float* conv_w1   = (const float*)d_in[17];
    const float* conv_b1   = (const float*)d_in[18];
    const float* conv_w2   = (const float*)d_in[19];
    const float* conv_b2   = (const float*)d_in[20];
    const float* ln_g      = (const float*)d_in[21];
    const float* ln_b      = (const float*)d_in[22];

    const int N = in_sizes[0] / 9;
    const int E = in_sizes[1] / 3;
    const int V = in_sizes[10] / (3 * DM);  // bond vocab (8) -> V^3 combos (512)
    const int nC = V * V * V;
    const long SZ = (long)DM * DM;

    // ---- workspace: WT | Q | h | T | key | ids3 (~170 MiB) ----
    char* ws = (char*)d_ws;
    size_t off = 0;
    f16* WT  = (f16*)(ws + off); off += ((size_t)12 * SZ * 2 + 4095) & ~(size_t)4095;
    f16* Q   = (f16*)(ws + off); off += ((size_t)CHUNK * DM * 2 + 4095) & ~(size_t)4095;
    f16* h   = (f16*)(ws + off); off += ((size_t)N * DM * 2 + 4095) & ~(size_t)4095;
    f16* T   = (f16*)(ws + off); off += ((size_t)((nC + 127) & ~127) * DM * 2 + 4095) & ~(size_t)4095;
    int* key = (int*)(ws + off); off += ((size_t)E * 4 + 4095) & ~(size_t)4095;
    int* ids3 = (int*)(ws + off); off += ((size_t)nC * 12 + 4095) & ~(size_t)4095;
    // d_out region (N*DM fp32 = 153.6MB): low half = f16 U scratch (<=76.9MB);
    // head/next parked at +120MB, only clobbered by the final fp32 LN write.
    f16*   U    = (f16*)d_out;
    int*   head = (int*)((char*)d_out + 120000000);
    int*   nxt  = head + N;

    dim3 tb(32, 8), tg(24, 24);
    transpose768<<<tg, tb, 0, stream>>>(atom_w1, WT + 0 * SZ);
    transpose768<<<tg, tb, 0, stream>>>(atom_w2, WT + 1 * SZ);
    transpose768<<<tg, tb, 0, stream>>>(bond_w1, WT + 2 * SZ);
    transpose768<<<tg, tb, 0, stream>>>(bond_w2, WT + 3 * SZ);
    for (int l = 0; l < NLAYERS; ++l) {
        transpose768<<<tg, tb, 0, stream>>>(conv_w1 + l * SZ, WT + (4 + l) * SZ);
        transpose768<<<tg, tb, 0, stream>>>(conv_w2 + l * SZ, WT + (8 + l) * SZ);
    }

    // build dst->edges linked list + per-edge combo key (edge data is constant)
    hipMemsetAsync(head, 0xFF, (size_t)N * 4, stream);  // head = -1
    build_list_kernel<<<(E + 255) / 256, 256, 0, stream>>>(ei, E, head, nxt);
    make_key_kernel<<<(E + 255) / 256, 256, 0, stream>>>(ea, E, V, key);

    int rtN = (N + 127) / 128;
    dim3 gn(6 * rtN);   // 1-D, XCD-chunked swizzle inside the kernel

    // AtomEncoder: h = gelu(LN(sum emb) @ w1 + b1) @ w2 + b2   (Q -> U(d_out) -> h)
    embed_ln_wave<<<(N + 3) / 4, 256, 0, stream>>>(x, 9, 128, atom_emb, atom_ln_g, atom_ln_b, Q, N);
    gemm768<ACT_GELU><<<gn, 256, 0, stream>>>(Q, WT + 0 * SZ, atom_b1, U, N);
    gemm768<ACT_NONE><<<gn, 256, 0, stream>>>(U, WT + 1 * SZ, atom_b2, h, N);

    // BondEncoder on the V^3 combo table only: Q -> U(d_out) -> T
    make_combo_ids<<<(nC + 255) / 256, 256, 0, stream>>>(V, nC, ids3);
    embed_ln_wave<<<(nC + 3) / 4, 256, 0, stream>>>(ids3, 3, V, bond_emb, bond_ln_g, bond_ln_b, Q, nC);
    dim3 gt(6 * ((nC + 127) / 128));
    gemm768<ACT_GELU><<<gt, 256, 0, stream>>>(Q, WT + 2 * SZ, bond_b1, U, nC);
    gemm768<ACT_NONE><<<gt, 256, 0, stream>>>(U, WT + 3 * SZ, bond_b2, T, nC);

    for (int l = 0; l < NLAYERS; ++l) {
        // z = h + sum_{j->i} relu(h[src] + T[key])  -> Q (f16), pure gather
        gather_agg_kernel<<<(N + 3) / 4, 256, 0, stream>>>(ei, head, nxt, key, h, T, Q, N);
        gemm768<ACT_RELU><<<gn, 256, 0, stream>>>(Q, WT + (4 + l) * SZ, conv_b1 + l * DM, U, N);  // U -> d_out
        gemm768<ACT_NONE><<<gn, 256, 0, stream>>>(U, WT + (8 + l) * SZ, conv_b2 + l * DM, Q, N);  // V -> Q
        if (l == NLAYERS - 1) {
            gelu_res_ln_wave<float><<<(N + 3) / 4, 256, 0, stream>>>(Q, h, ln_g + l * DM, ln_b + l * DM, (float*)d_out, N);
        } else {
            gelu_res_ln_wave<f16><<<(N + 3) / 4, 256, 0, stream>>>(Q, h, ln_g + l * DM, ln_b + l * DM, h, N);
        }
    }
}